// Round 1
// baseline (1507.684 us; speedup 1.0000x reference)
//
#include <hip/hip_runtime.h>

// ---------------------------------------------------------------------------
// GRU (T=256, B=1024, IN=128, H=256) + per-step BatchNorm, MI355X.
// R6->R7: (1) y-GEMM fused into the recurrence (h(t+1) A-frags are already in
// the LDS dbuf; +8 MFMA/wave/step, ygemm kernel deleted); (2) residency remap:
// AGPR = kt0-3 of all 8 gate groups, LDS = r0/r1 kt4-7 + y kt0-7, streamed =
// z/in/hn kt4-7 -> every streamed tile first used at kt>=4 (>=4 iter lead vs 0);
// (3) v_rcp/v_exp2 activations (kills 24 correctly-rounded div seqs per
// thread-step); (4) lgkm-only barrier (no vmcnt(0) drain of global stores on
// the per-step critical path).
// ---------------------------------------------------------------------------

typedef _Float16 half8 __attribute__((ext_vector_type(8)));
typedef float floatx4 __attribute__((ext_vector_type(4)));
typedef unsigned uintx4 __attribute__((ext_vector_type(4)));

#define EPS_BN 1e-5f

// ws layout (bytes):
//   [0,       524288)   wc: folded gate weights, 16 cgs x 32 tiles x 1 KB
//   [524288, 1114112)   w0: step-0 weights, 16 cgs x 36 tiles x 1 KB
//   [1114112,1179648)   wl: W_lin B-frags, 64 tiles x 1 KB
//   [1179648,1183744)   bias0: 256 x float4
//   [1183744,1187840)   bc: 256 x float4 folded biases
//   [1187840,1449984)   stats: 256 t x 128 c x {sum,sumsq} fp32 (memset 0)
#define WS_WC 0
#define WS_W0 524288
#define WS_WL 1114112
#define WS_B0 1179648
#define WS_BC 1183744
#define WS_ST 1187840

static __device__ __forceinline__ unsigned short f2h(float f) {
    union { _Float16 h; unsigned short u; } v;
    v.h = (_Float16)f;                      // v_cvt_f16_f32, RNE
    return v.u;
}
static __device__ __forceinline__ half8 as_h8(uint4 v) {
    union { uint4 u; half8 h; } x; x.u = v; return x.h;
}
// Load a 16B weight fragment and force it into AGPRs (opaque, non-remat).
static __device__ __forceinline__ half8 ld_agpr(const uint4* p) {
    uintx4 v = *(const uintx4*)p;
    asm volatile("; wpin" : "+a"(v));
    union { uintx4 u; half8 h; } x; x.u = v; return x.h;
}
// Fast activations: v_rcp_f32 + v_exp_f32 (1 ulp each) instead of the
// ~10-instr correctly-rounded f32 divide sequence hipcc emits for 1.0f/x.
static __device__ __forceinline__ float sigm(float x) {
    return __builtin_amdgcn_rcpf(1.0f + __builtin_amdgcn_exp2f(-1.442695041f * x));
}
static __device__ __forceinline__ float tanh_fast(float x) {
    return 1.0f - 2.0f * __builtin_amdgcn_rcpf(1.0f + __builtin_amdgcn_exp2f(2.885390082f * x));
}
// Workgroup barrier that drains LDS only (no vmcnt(0) store-drain). Safe:
// cross-wave data exchange is exclusively through LDS; global writes are
// never re-read inside this kernel.
static __device__ __forceinline__ void bar_lgkm() {
    asm volatile("s_waitcnt lgkmcnt(0)\n\ts_barrier" ::: "memory");
}
#define MFMA16(A, B, C) __builtin_amdgcn_mfma_f32_16x16x32_f16((A), (B), (C), 0, 0, 0)

// ---------------------------------------------------------------------------
// pack_w0: original weights -> fp16 B-frag tiles + wl + bias0. (R3-verified)
// B-frag 16x16x32: lane l holds B[n0+(l&15)][k0+(l>>4)*8+j].
// ---------------------------------------------------------------------------
__global__ void pack_w0_kernel(const float* __restrict__ W_ih, const float* __restrict__ W_hh,
                               const float* __restrict__ W_lin, const float* __restrict__ b_ih,
                               const float* __restrict__ b_hh,
                               uint4* __restrict__ w0, uint4* __restrict__ wl,
                               float4* __restrict__ bias0)
{
    int i = blockIdx.x * 256 + threadIdx.x;
    if (i < 36864) {                       // 576 w0 tiles x 64 lanes
        int lane = i & 63, tile = i >> 6;
        int w = tile / 36, rem = tile - w * 36;
        int g = rem / 12, kt = rem - g * 12;
        int n = g * 256 + (w << 4) + (lane & 15);
        int k0 = (kt << 5) + ((lane >> 4) << 3);
        const float* p = (k0 < 128) ? (W_ih + n * 128 + k0)
                                    : (W_hh + n * 256 + (k0 - 128));
        unsigned short h[8];
        #pragma unroll
        for (int j = 0; j < 8; ++j) h[j] = f2h(p[j]);
        uint4 v;
        v.x = (unsigned)h[0] | ((unsigned)h[1] << 16);
        v.y = (unsigned)h[2] | ((unsigned)h[3] << 16);
        v.z = (unsigned)h[4] | ((unsigned)h[5] << 16);
        v.w = (unsigned)h[6] | ((unsigned)h[7] << 16);
        w0[i] = v;
    } else if (i < 40960) {                // 64 wl tiles x 64 lanes
        int i2 = i - 36864;
        int lane = i2 & 63, tile = i2 >> 6;        // tile = nt*8 + kt
        int n = (tile >> 3) * 16 + (lane & 15);
        int k0 = ((tile & 7) << 5) + ((lane >> 4) << 3);
        const float* p = W_lin + n * 256 + k0;
        unsigned short h[8];
        #pragma unroll
        for (int j = 0; j < 8; ++j) h[j] = f2h(p[j]);
        uint4 v;
        v.x = (unsigned)h[0] | ((unsigned)h[1] << 16);
        v.y = (unsigned)h[2] | ((unsigned)h[3] << 16);
        v.z = (unsigned)h[4] | ((unsigned)h[5] << 16);
        v.w = (unsigned)h[6] | ((unsigned)h[7] << 16);
        wl[i2] = v;
    } else if (i < 41216) {
        int cb = i - 40960;
        bias0[cb] = make_float4(b_ih[cb] + b_hh[cb],
                                b_ih[256 + cb] + b_hh[256 + cb],
                                b_ih[512 + cb], b_hh[512 + cb]);
    }
}

// ---------------------------------------------------------------------------
// pack_wc: folded weights (fp32 fold, one fp16 round) + folded biases.
// tile idx = cg*32 + g*8 + kt; g: 0=r (W_ih_r@W_lin + W_hh_r), 1=z,
// 2=in (W_ihn@W_lin), 3=hn (W_hhn). (R5-verified)
// ---------------------------------------------------------------------------
__global__ void pack_wc_kernel(const float* __restrict__ W_ih, const float* __restrict__ W_hh,
                               const float* __restrict__ W_lin, const float* __restrict__ b_ih,
                               const float* __restrict__ b_hh, const float* __restrict__ b_lin,
                               uint4* __restrict__ wc, float4* __restrict__ bc)
{
    int i = blockIdx.x * 256 + threadIdx.x;
    if (i < 32768) {                       // 512 wc tiles x 64 lanes
        int lane = i & 63, tile = i >> 6;
        int w = tile >> 5, r = tile & 31;
        int g = r >> 3, kt = r & 7;
        int c = (w << 4) + (lane & 15);
        int k0 = (kt << 5) + ((lane >> 4) << 3);
        float s[8];
        if (g == 3) {
            #pragma unroll
            for (int j = 0; j < 8; ++j) s[j] = W_hh[(512 + c) * 256 + k0 + j];
        } else {
            int row = g * 256 + c;
            const float* wi = W_ih + row * 128;
            #pragma unroll
            for (int j = 0; j < 8; ++j) s[j] = 0.0f;
            for (int ii = 0; ii < 128; ++ii) {
                float wv = wi[ii];
                const float* wrow = W_lin + ii * 256 + k0;
                #pragma unroll
                for (int j = 0; j < 8; ++j) s[j] += wv * wrow[j];
            }
            if (g < 2) {
                #pragma unroll
                for (int j = 0; j < 8; ++j) s[j] += W_hh[row * 256 + k0 + j];
            }
        }
        unsigned short h[8];
        #pragma unroll
        for (int j = 0; j < 8; ++j) h[j] = f2h(s[j]);
        uint4 v;
        v.x = (unsigned)h[0] | ((unsigned)h[1] << 16);
        v.y = (unsigned)h[2] | ((unsigned)h[3] << 16);
        v.z = (unsigned)h[4] | ((unsigned)h[5] << 16);
        v.w = (unsigned)h[6] | ((unsigned)h[7] << 16);
        wc[i] = v;
    } else if (i < 33024) {
        int c = i - 32768;
        float d0 = 0.f, d1 = 0.f, d2 = 0.f;
        for (int ii = 0; ii < 128; ++ii) {
            float bl = b_lin[ii];
            d0 += bl * W_ih[c * 128 + ii];
            d1 += bl * W_ih[(256 + c) * 128 + ii];
            d2 += bl * W_ih[(512 + c) * 128 + ii];
        }
        bc[c] = make_float4(b_ih[c] + b_hh[c] + d0,
                            b_ih[256 + c] + b_hh[256 + c] + d1,
                            b_ih[512 + c] + d2,
                            b_hh[512 + c]);
    }
}

// ---------------------------------------------------------------------------
// Recurrence + fused y-GEMM: 64 blocks x 512 thr (8 waves, 2/SIMD). Block owns
// 16 batch rows; wave w owns gate col-groups {w, w+8} and y col-group w.
// Residency per wave (72 tiles total):
//   AGPR 32: kt0-3 of r0,z0,in0,hn0,r1,z1,in1,hn1
//   LDS  16: r0 kt4-7 [slots 0-3], r1 kt4-7 [4-7], y kt0-7 [8-15]
//   streamed 24/step: z/in/hn kt4-7 (first use kt>=4)
// LDS (uint4): [0,1024) h-frag dbuf | [1024,1280) xbuf (t0 only) |
// [1280,9472) per-wave weight tiles. One lgkm-only barrier per step.
// ---------------------------------------------------------------------------
__global__ __launch_bounds__(512, 2) void gru_kernel(
    const float* __restrict__ inputs,
    const float* __restrict__ hidden,
    const uint4* __restrict__ wc,
    const uint4* __restrict__ w0,
    const uint4* __restrict__ wl,
    const float4* __restrict__ bias0,
    const float4* __restrict__ bcp,
    const float* __restrict__ b_lin,
    float* __restrict__ out,
    float* __restrict__ stats)
{
    __shared__ uint4 lds[9472];            // 151552 B

    const int tid  = threadIdx.x;
    const int lane = tid & 63;
    const int w    = tid >> 6;             // wave 0..7
    const int quad = lane >> 4;
    const int nc   = lane & 15;
    const int r0   = blockIdx.x << 4;
    const int c0   = (w << 4) + nc;
    const int c1   = 128 + c0;
    const float4 bc0 = bcp[c0];
    const float4 bc1 = bcp[c1];
    const float  bl  = b_lin[c0];          // y col == c0
    const uint4* wcw0 = wc + (size_t)w * 2048;        // 32 tiles * 64
    const uint4* wcw1 = wc + (size_t)(w + 8) * 2048;

    // ---- AGPR-pinned tiles: kt0-3 of all 8 gate groups
    half8 pr0[4], pz0[4], pi0[4], ph0[4], pr1[4], pz1[4], pi1[4], ph1[4];
    #pragma unroll
    for (int kt = 0; kt < 4; ++kt) {
        pr0[kt] = ld_agpr(&wcw0[kt * 64 + lane]);
        pz0[kt] = ld_agpr(&wcw0[(8 + kt) * 64 + lane]);
        pi0[kt] = ld_agpr(&wcw0[(16 + kt) * 64 + lane]);
        ph0[kt] = ld_agpr(&wcw0[(24 + kt) * 64 + lane]);
        pr1[kt] = ld_agpr(&wcw1[kt * 64 + lane]);
        pz1[kt] = ld_agpr(&wcw1[(8 + kt) * 64 + lane]);
        pi1[kt] = ld_agpr(&wcw1[(16 + kt) * 64 + lane]);
        ph1[kt] = ld_agpr(&wcw1[(24 + kt) * 64 + lane]);
    }

    // ---- LDS-resident tiles: r0 kt4-7, r1 kt4-7, y kt0-7
    const int wbase = 1280 + (w << 10);
    #pragma unroll
    for (int i = 0; i < 4; ++i) {
        lds[wbase + (i << 6) + lane]       = wcw0[(4 + i) * 64 + lane];
        lds[wbase + ((4 + i) << 6) + lane] = wcw1[(4 + i) * 64 + lane];
    }
    #pragma unroll
    for (int i = 0; i < 8; ++i)
        lds[wbase + ((8 + i) << 6) + lane] = wl[(size_t)(w * 8 + i) * 64 + lane];

    // fp32 master hidden state: rows quad*4+d; [0..3]=c0, [4..7]=c1
    float hreg[8];
    #pragma unroll
    for (int d = 0; d < 4; ++d) {
        hreg[d]     = hidden[(r0 + (quad << 2) + d) * 256 + c0];
        hreg[4 + d] = hidden[(r0 + (quad << 2) + d) * 256 + c1];
    }

    // A-frag write addressing: A[m][k]: kt=k>>5, k'=k&31,
    // frag lane=(k'>>3)*16+m, j=k'&7; u16 idx=(kt*64+lane_f)*8+j
    unsigned short* lds_u16 = (unsigned short*)lds;
    const int kp  = ((w & 1) << 4) + nc;
    const int lf  = ((kp >> 3) << 4) + (quad << 2);
    const int hfb0 = (((w >> 1) * 64 + lf) << 3) + (kp & 7);
    const int hfb1 = (((4 + (w >> 1)) * 64 + lf) << 3) + (kp & 7);

    // init h(0) frags -> buf0
    for (int idx = tid; idx < 2048; idx += 512) {
        int ktl = idx >> 8;
        int rem = idx & 255;
        int lfr = rem >> 2, jg = rem & 3;
        int m = lfr & 15;
        int hc = ktl * 32 + (lfr >> 4) * 8 + jg * 2;
        const float* p = hidden + (r0 + m) * 256 + hc;
        unsigned pk = (unsigned)f2h(p[0]) | ((unsigned)f2h(p[1]) << 16);
        ((unsigned*)lds)[(ktl * 64 + lfr) * 4 + jg] = pk;
    }
    // init x frags -> xbuf
    for (int idx = tid; idx < 1024; idx += 512) {
        int kt = idx >> 8, lfr = (idx >> 2) & 63, jg = idx & 3;
        int m = lfr & 15;
        int k0 = (kt << 5) + ((lfr >> 4) << 3) + (jg << 1);
        const float* p = inputs + (r0 + m) * 128 + k0;
        unsigned pk = (unsigned)f2h(p[0]) | ((unsigned)f2h(p[1]) << 16);
        ((unsigned*)lds)[(1024 + (kt << 6) + lfr) * 4 + jg] = pk;
    }
    __syncthreads();

    // ---- t = 0: K=384 on [x|h] with original w0 (streamed once)
    {
        #pragma unroll
        for (int g2 = 0; g2 < 2; ++g2) {
            const uint4* ww = w0 + (size_t)(g2 ? (w + 8) : w) * 2304;  // 36*64
            floatx4 ar = {0.f,0.f,0.f,0.f}, az = {0.f,0.f,0.f,0.f};
            floatx4 ain = {0.f,0.f,0.f,0.f}, ahn = {0.f,0.f,0.f,0.f};
            #pragma unroll
            for (int kt = 0; kt < 12; ++kt) {
                half8 A = as_h8(kt < 4 ? lds[1024 + (kt << 6) + lane]
                                       : lds[((kt - 4) << 6) + lane]);
                ar = MFMA16(A, as_h8(ww[kt * 64 + lane]), ar);
                az = MFMA16(A, as_h8(ww[(12 + kt) * 64 + lane]), az);
                if (kt < 4)
                    ain = MFMA16(A, as_h8(ww[(24 + kt) * 64 + lane]), ain);
                else
                    ahn = MFMA16(A, as_h8(ww[(24 + kt) * 64 + lane]), ahn);
            }
            const int cc = g2 ? c1 : c0;
            const int hfb = g2 ? hfb1 : hfb0;
            float4 b0 = bias0[cc];
            #pragma unroll
            for (int d = 0; d < 4; ++d) {
                float rr = sigm(ar[d] + b0.x);
                float zz = sigm(az[d] + b0.y);
                float nn = tanh_fast(ain[d] + b0.z + rr * (ahn[d] + b0.w));
                float hnew = (1.0f - zz) * nn + zz * hreg[(g2 << 2) + d];
                hreg[(g2 << 2) + d] = hnew;
                lds_u16[4096 + hfb + (d << 3)] = f2h(hnew);   // buf1
            }
        }
        bar_lgkm();
    }

    for (int t = 1; t < 256; ++t) {
        const int rb   = (t & 1) << 9;                 // read buf (uint4)
        const int wb16 = (((t + 1) & 1) << 9) << 3;    // write buf (u16)

        // opaque per-iteration pointers: streamed tiles cannot be hoisted
        const uint4* s0p = wcw0 + lane;
        const uint4* s1p = wcw1 + lane;
        asm("" : "+v"(s0p), "+v"(s1p));

        // streamed tiles: z/in/hn kt4-7, batch for kt issued >=1 iter early,
        // first consumer is kt=4 -> >=4 iterations of L2-latency cover.
        uint4 sz0[4], si0[4], sh0[4], sz1[4], si1[4], sh1[4];
        sz0[0] = s0p[12 * 64]; si0[0] = s0p[20 * 64]; sh0[0] = s0p[28 * 64];
        sz1[0] = s1p[12 * 64]; si1[0] = s1p[20 * 64]; sh1[0] = s1p[28 * 64];

        floatx4 acr0 = {0.f,0.f,0.f,0.f}, acz0 = {0.f,0.f,0.f,0.f};
        floatx4 aci0 = {0.f,0.f,0.f,0.f}, ach0 = {0.f,0.f,0.f,0.f};
        floatx4 acr1 = {0.f,0.f,0.f,0.f}, acz1 = {0.f,0.f,0.f,0.f};
        floatx4 aci1 = {0.f,0.f,0.f,0.f}, ach1 = {0.f,0.f,0.f,0.f};

        #pragma unroll
        for (int kt = 0; kt < 4; ++kt) {               // B from AGPR pins
            half8 A = as_h8(lds[rb + (kt << 6) + lane]);
            if (kt == 1) {
                sz0[1] = s0p[13 * 64]; si0[1] = s0p[21 * 64]; sh0[1] = s0p[29 * 64];
                sz1[1] = s1p[13 * 64]; si1[1] = s1p[21 * 64]; sh1[1] = s1p[29 * 64];
            }
            if (kt == 2) {
                sz0[2] = s0p[14 * 64]; si0[2] = s0p[22 * 64]; sh0[2] = s0p[30 * 64];
                sz1[2] = s1p[14 * 64]; si1[2] = s1p[22 * 64]; sh1[2] = s1p[30 * 64];
            }
            if (kt == 3) {
                sz0[3] = s0p[15 * 64]; si0[3] = s0p[23 * 64]; sh0[3] = s0p[31 * 64];
                sz1[3] = s1p[15 * 64]; si1[3] = s1p[23 * 64]; sh1[3] = s1p[31 * 64];
            }
            acr0 = MFMA16(A, pr0[kt], acr0);
            acr1 = MFMA16(A, pr1[kt], acr1);
            acz0 = MFMA16(A, pz0[kt], acz0);
            acz1 = MFMA16(A, pz1[kt], acz1);
            aci0 = MFMA16(A, pi0[kt], aci0);
            aci1 = MFMA16(A, pi1[kt], aci1);
            ach0 = MFMA16(A, ph0[kt], ach0);
            ach1 = MFMA16(A, ph1[kt], ach1);
        }
        #pragma unroll
        for (int kt = 0; kt < 4; ++kt) {               // kt+4: r from LDS, rest streamed
            half8 A = as_h8(lds[rb + ((4 + kt) << 6) + lane]);
            acr0 = MFMA16(A, as_h8(lds[wbase + (kt << 6) + lane]), acr0);
            acr1 = MFMA16(A, as_h8(lds[wbase + ((4 + kt) << 6) + lane]), acr1);
            acz0 = MFMA16(A, as_h8(sz0[kt]), acz0);
            acz1 = MFMA16(A, as_h8(sz1[kt]), acz1);
            aci0 = MFMA16(A, as_h8(si0[kt]), aci0);
            aci1 = MFMA16(A, as_h8(si1[kt]), aci1);
            ach0 = MFMA16(A, as_h8(sh0[kt]), ach0);
            ach1 = MFMA16(A, as_h8(sh1[kt]), ach1);
        }

        // gate epilogue -> h(t+1) frags into write buffer
        #pragma unroll
        for (int d = 0; d < 4; ++d) {
            float rr = sigm(acr0[d] + bc0.x);
            float zz = sigm(acz0[d] + bc0.y);
            float nn = tanh_fast(aci0[d] + bc0.z + rr * (ach0[d] + bc0.w));
            float hnew = (1.0f - zz) * nn + zz * hreg[d];
            hreg[d] = hnew;
            lds_u16[wb16 + hfb0 + (d << 3)] = f2h(hnew);
        }
        #pragma unroll
        for (int d = 0; d < 4; ++d) {
            float rr = sigm(acr1[d] + bc1.x);
            float zz = sigm(acz1[d] + bc1.y);
            float nn = tanh_fast(aci1[d] + bc1.z + rr * (ach1[d] + bc1.w));
            float hnew = (1.0f - zz) * nn + zz * hreg[4 + d];
            hreg[4 + d] = hnew;
            lds_u16[wb16 + hfb1 + (d << 3)] = f2h(hnew);
        }

        // fused y-GEMM: y[t-1] = h(t) @ W_lin^T + b_lin (h(t) frags = buf[rb])
        {
            floatx4 acy = {0.f,0.f,0.f,0.f};
            #pragma unroll
            for (int kt = 0; kt < 8; ++kt) {
                half8 A = as_h8(lds[rb + (kt << 6) + lane]);
                acy = MFMA16(A, as_h8(lds[wbase + ((8 + kt) << 6) + lane]), acy);
            }
            float s1 = 0.f, s2 = 0.f;
            float* orow = out + ((size_t)(t - 1) * 1024 + r0 + (quad << 2)) * 128 + c0;
            #pragma unroll
            for (int d = 0; d < 4; ++d) {
                float y = acy[d] + bl;
                orow[(size_t)d << 7] = y;
                s1 += y; s2 += y * y;
            }
            s1 += __shfl_xor(s1, 16); s1 += __shfl_xor(s1, 32);
            s2 += __shfl_xor(s2, 16); s2 += __shfl_xor(s2, 32);
            if (lane < 16) {
                int si = (((t - 1) << 7) + (w << 4) + lane) << 1;
                atomicAdd(&stats[si], s1);
                atomicAdd(&stats[si + 1], s2);
            }
        }
        bar_lgkm();
    }

    // final y for t=255: h(256) frags are in buf0
    {
        floatx4 acy = {0.f,0.f,0.f,0.f};
        #pragma unroll
        for (int kt = 0; kt < 8; ++kt) {
            half8 A = as_h8(lds[(kt << 6) + lane]);
            acy = MFMA16(A, as_h8(lds[wbase + ((8 + kt) << 6) + lane]), acy);
        }
        float s1 = 0.f, s2 = 0.f;
        float* orow = out + ((size_t)255 * 1024 + r0 + (quad << 2)) * 128 + c0;
        #pragma unroll
        for (int d = 0; d < 4; ++d) {
            float y = acy[d] + bl;
            orow[(size_t)d << 7] = y;
            s1 += y; s2 += y * y;
        }
        s1 += __shfl_xor(s1, 16); s1 += __shfl_xor(s1, 32);
        s2 += __shfl_xor(s2, 16); s2 += __shfl_xor(s2, 32);
        if (lane < 16) {
            int si = ((255 << 7) + (w << 4) + lane) << 1;
            atomicAdd(&stats[si], s1);
            atomicAdd(&stats[si + 1], s2);
        }
    }
}

// ---------------------------------------------------------------------------
// Normalize: in-place BN from raw sums. Biased variance, eps inside sqrt.
// ---------------------------------------------------------------------------
__global__ void norm_kernel(float* __restrict__ out, const float* __restrict__ stats)
{
    __shared__ float smean[128], sscale[128];
    int t = blockIdx.x >> 2, q = blockIdx.x & 3;
    int tid = threadIdx.x;
    if (tid < 128) {
        int si = ((t << 7) + tid) << 1;
        float mean = stats[si] * (1.0f / 1024.0f);
        float var = stats[si + 1] * (1.0f / 1024.0f) - mean * mean;
        smean[tid] = mean;
        sscale[tid] = rsqrtf(var + EPS_BN);
    }
    __syncthreads();
    float4* p = (float4*)(out + ((size_t)t << 17) + ((size_t)q << 15));
    for (int i = tid; i < 8192; i += 256) {
        int cc = (i & 31) << 2;
        float4 v = p[i];
        v.x = (v.x - smean[cc])     * sscale[cc];
        v.y = (v.y - smean[cc + 1]) * sscale[cc + 1];
        v.z = (v.z - smean[cc + 2]) * sscale[cc + 2];
        v.w = (v.w - smean[cc + 3]) * sscale[cc + 3];
        p[i] = v;
    }
}

extern "C" void kernel_launch(void* const* d_in, const int* in_sizes, int n_in,
                              void* d_out, int out_size, void* d_ws, size_t ws_size,
                              hipStream_t stream) {
    (void)in_sizes; (void)n_in; (void)out_size; (void)ws_size;
    const float* inputs = (const float*)d_in[0];
    const float* hidden = (const float*)d_in[1];
    const float* W_ih   = (const float*)d_in[2];
    const float* b_ih   = (const float*)d_in[3];
    const float* W_hh   = (const float*)d_in[4];
    const float* b_hh   = (const float*)d_in[5];
    const float* W_lin  = (const float*)d_in[6];
    const float* b_lin  = (const float*)d_in[7];

    char* ws = (char*)d_ws;
    uint4*  wcp   = (uint4*)(ws + WS_WC);
    uint4*  w0p   = (uint4*)(ws + WS_W0);
    uint4*  wlp   = (uint4*)(ws + WS_WL);
    float4* bias0 = (float4*)(ws + WS_B0);
    float4* bcp   = (float4*)(ws + WS_BC);
    float*  stats = (float*)(ws + WS_ST);

    hipMemsetAsync(stats, 0, 262144, stream);
    pack_w0_kernel<<<161, 256, 0, stream>>>(W_ih, W_hh, W_lin, b_ih, b_hh, w0p, wlp, bias0);
    pack_wc_kernel<<<129, 256, 0, stream>>>(W_ih, W_hh, W_lin, b_ih, b_hh, b_lin, wcp, bcp);
    gru_kernel<<<64, 512, 0, stream>>>(inputs, hidden, wcp, w0p, wlp, bias0, bcp, b_lin,
                                       (float*)d_out, stats);
    norm_kernel<<<1024, 256, 0, stream>>>((float*)d_out, stats);
}

// Round 2
// 1401.313 us; speedup vs baseline: 1.0759x; 1.0759x over previous
//
#include <hip/hip_runtime.h>

// ---------------------------------------------------------------------------
// GRU (T=256, B=1024, IN=128, H=256) + per-step BatchNorm, MI355X.
// R7->R8: atomics removed from the recurrence. R7's regression (845->1352us)
// was the per-step stats atomicAdds: all 64 blocks in lockstep hammer the same
// 16 cache lines each step (64-way same-address RMW), and in-order vmcnt
// retirement gates the NEXT step's streamed weight-load waits on those slow
// atomics. Fix: gru y-epilogue = 4 plain fp32 stores only; BN stats computed
// by a dedicated stats_kernel pass over `out` (one block per t, coalesced);
// norm applies precomputed {mean, scale}. Keeps R7's y-GEMM fusion, fast
// rcp/exp2 activations, kt>=4 streamed-tile lead, lgkm-only barrier.
// ---------------------------------------------------------------------------

typedef _Float16 half8 __attribute__((ext_vector_type(8)));
typedef float floatx4 __attribute__((ext_vector_type(4)));
typedef unsigned uintx4 __attribute__((ext_vector_type(4)));

#define EPS_BN 1e-5f

// ws layout (bytes):
//   [0,       524288)   wc: folded gate weights, 16 cgs x 32 tiles x 1 KB
//   [524288, 1114112)   w0: step-0 weights, 16 cgs x 36 tiles x 1 KB
//   [1114112,1179648)   wl: W_lin B-frags, 64 tiles x 1 KB
//   [1179648,1183744)   bias0: 256 x float4
//   [1183744,1187840)   bc: 256 x float4 folded biases
//   [1187840,1449984)   stats: 256 t x 128 c x {mean, scale} fp32
#define WS_WC 0
#define WS_W0 524288
#define WS_WL 1114112
#define WS_B0 1179648
#define WS_BC 1183744
#define WS_ST 1187840

static __device__ __forceinline__ unsigned short f2h(float f) {
    union { _Float16 h; unsigned short u; } v;
    v.h = (_Float16)f;                      // v_cvt_f16_f32, RNE
    return v.u;
}
static __device__ __forceinline__ half8 as_h8(uint4 v) {
    union { uint4 u; half8 h; } x; x.u = v; return x.h;
}
// Load a 16B weight fragment and force it into AGPRs (opaque, non-remat).
static __device__ __forceinline__ half8 ld_agpr(const uint4* p) {
    uintx4 v = *(const uintx4*)p;
    asm volatile("; wpin" : "+a"(v));
    union { uintx4 u; half8 h; } x; x.u = v; return x.h;
}
// Fast activations: v_rcp_f32 + v_exp_f32 (1 ulp each) instead of the
// ~10-instr correctly-rounded f32 divide sequence hipcc emits for 1.0f/x.
static __device__ __forceinline__ float sigm(float x) {
    return __builtin_amdgcn_rcpf(1.0f + __builtin_amdgcn_exp2f(-1.442695041f * x));
}
static __device__ __forceinline__ float tanh_fast(float x) {
    return 1.0f - 2.0f * __builtin_amdgcn_rcpf(1.0f + __builtin_amdgcn_exp2f(2.885390082f * x));
}
// Workgroup barrier that drains LDS only (no vmcnt(0) store-drain). Safe:
// cross-wave data exchange is exclusively through LDS; global writes are
// never re-read inside this kernel.
static __device__ __forceinline__ void bar_lgkm() {
    asm volatile("s_waitcnt lgkmcnt(0)\n\ts_barrier" ::: "memory");
}
#define MFMA16(A, B, C) __builtin_amdgcn_mfma_f32_16x16x32_f16((A), (B), (C), 0, 0, 0)

// ---------------------------------------------------------------------------
// pack_w0: original weights -> fp16 B-frag tiles + wl + bias0. (R3-verified)
// B-frag 16x16x32: lane l holds B[n0+(l&15)][k0+(l>>4)*8+j].
// ---------------------------------------------------------------------------
__global__ void pack_w0_kernel(const float* __restrict__ W_ih, const float* __restrict__ W_hh,
                               const float* __restrict__ W_lin, const float* __restrict__ b_ih,
                               const float* __restrict__ b_hh,
                               uint4* __restrict__ w0, uint4* __restrict__ wl,
                               float4* __restrict__ bias0)
{
    int i = blockIdx.x * 256 + threadIdx.x;
    if (i < 36864) {                       // 576 w0 tiles x 64 lanes
        int lane = i & 63, tile = i >> 6;
        int w = tile / 36, rem = tile - w * 36;
        int g = rem / 12, kt = rem - g * 12;
        int n = g * 256 + (w << 4) + (lane & 15);
        int k0 = (kt << 5) + ((lane >> 4) << 3);
        const float* p = (k0 < 128) ? (W_ih + n * 128 + k0)
                                    : (W_hh + n * 256 + (k0 - 128));
        unsigned short h[8];
        #pragma unroll
        for (int j = 0; j < 8; ++j) h[j] = f2h(p[j]);
        uint4 v;
        v.x = (unsigned)h[0] | ((unsigned)h[1] << 16);
        v.y = (unsigned)h[2] | ((unsigned)h[3] << 16);
        v.z = (unsigned)h[4] | ((unsigned)h[5] << 16);
        v.w = (unsigned)h[6] | ((unsigned)h[7] << 16);
        w0[i] = v;
    } else if (i < 40960) {                // 64 wl tiles x 64 lanes
        int i2 = i - 36864;
        int lane = i2 & 63, tile = i2 >> 6;        // tile = nt*8 + kt
        int n = (tile >> 3) * 16 + (lane & 15);
        int k0 = ((tile & 7) << 5) + ((lane >> 4) << 3);
        const float* p = W_lin + n * 256 + k0;
        unsigned short h[8];
        #pragma unroll
        for (int j = 0; j < 8; ++j) h[j] = f2h(p[j]);
        uint4 v;
        v.x = (unsigned)h[0] | ((unsigned)h[1] << 16);
        v.y = (unsigned)h[2] | ((unsigned)h[3] << 16);
        v.z = (unsigned)h[4] | ((unsigned)h[5] << 16);
        v.w = (unsigned)h[6] | ((unsigned)h[7] << 16);
        wl[i2] = v;
    } else if (i < 41216) {
        int cb = i - 40960;
        bias0[cb] = make_float4(b_ih[cb] + b_hh[cb],
                                b_ih[256 + cb] + b_hh[256 + cb],
                                b_ih[512 + cb], b_hh[512 + cb]);
    }
}

// ---------------------------------------------------------------------------
// pack_wc: folded weights (fp32 fold, one fp16 round) + folded biases.
// tile idx = cg*32 + g*8 + kt; g: 0=r (W_ih_r@W_lin + W_hh_r), 1=z,
// 2=in (W_ihn@W_lin), 3=hn (W_hhn). (R5-verified)
// ---------------------------------------------------------------------------
__global__ void pack_wc_kernel(const float* __restrict__ W_ih, const float* __restrict__ W_hh,
                               const float* __restrict__ W_lin, const float* __restrict__ b_ih,
                               const float* __restrict__ b_hh, const float* __restrict__ b_lin,
                               uint4* __restrict__ wc, float4* __restrict__ bc)
{
    int i = blockIdx.x * 256 + threadIdx.x;
    if (i < 32768) {                       // 512 wc tiles x 64 lanes
        int lane = i & 63, tile = i >> 6;
        int w = tile >> 5, r = tile & 31;
        int g = r >> 3, kt = r & 7;
        int c = (w << 4) + (lane & 15);
        int k0 = (kt << 5) + ((lane >> 4) << 3);
        float s[8];
        if (g == 3) {
            #pragma unroll
            for (int j = 0; j < 8; ++j) s[j] = W_hh[(512 + c) * 256 + k0 + j];
        } else {
            int row = g * 256 + c;
            const float* wi = W_ih + row * 128;
            #pragma unroll
            for (int j = 0; j < 8; ++j) s[j] = 0.0f;
            for (int ii = 0; ii < 128; ++ii) {
                float wv = wi[ii];
                const float* wrow = W_lin + ii * 256 + k0;
                #pragma unroll
                for (int j = 0; j < 8; ++j) s[j] += wv * wrow[j];
            }
            if (g < 2) {
                #pragma unroll
                for (int j = 0; j < 8; ++j) s[j] += W_hh[row * 256 + k0 + j];
            }
        }
        unsigned short h[8];
        #pragma unroll
        for (int j = 0; j < 8; ++j) h[j] = f2h(s[j]);
        uint4 v;
        v.x = (unsigned)h[0] | ((unsigned)h[1] << 16);
        v.y = (unsigned)h[2] | ((unsigned)h[3] << 16);
        v.z = (unsigned)h[4] | ((unsigned)h[5] << 16);
        v.w = (unsigned)h[6] | ((unsigned)h[7] << 16);
        wc[i] = v;
    } else if (i < 33024) {
        int c = i - 32768;
        float d0 = 0.f, d1 = 0.f, d2 = 0.f;
        for (int ii = 0; ii < 128; ++ii) {
            float bl = b_lin[ii];
            d0 += bl * W_ih[c * 128 + ii];
            d1 += bl * W_ih[(256 + c) * 128 + ii];
            d2 += bl * W_ih[(512 + c) * 128 + ii];
        }
        bc[c] = make_float4(b_ih[c] + b_hh[c] + d0,
                            b_ih[256 + c] + b_hh[256 + c] + d1,
                            b_ih[512 + c] + d2,
                            b_hh[512 + c]);
    }
}

// ---------------------------------------------------------------------------
// Recurrence + fused y-GEMM: 64 blocks x 512 thr (8 waves, 2/SIMD). Block owns
// 16 batch rows; wave w owns gate col-groups {w, w+8} and y col-group w.
// Residency per wave (72 tiles total):
//   AGPR 32: kt0-3 of r0,z0,in0,hn0,r1,z1,in1,hn1
//   LDS  16: r0 kt4-7 [slots 0-3], r1 kt4-7 [4-7], y kt0-7 [8-15]
//   streamed 24/step: z/in/hn kt4-7 (first use kt>=4)
// Per-step globals: 4 plain fp32 y-stores per thread. NO atomics (R8).
// LDS (uint4): [0,1024) h-frag dbuf | [1024,1280) xbuf (t0 only) |
// [1280,9472) per-wave weight tiles. One lgkm-only barrier per step.
// ---------------------------------------------------------------------------
__global__ __launch_bounds__(512, 2) void gru_kernel(
    const float* __restrict__ inputs,
    const float* __restrict__ hidden,
    const uint4* __restrict__ wc,
    const uint4* __restrict__ w0,
    const uint4* __restrict__ wl,
    const float4* __restrict__ bias0,
    const float4* __restrict__ bcp,
    const float* __restrict__ b_lin,
    float* __restrict__ out)
{
    __shared__ uint4 lds[9472];            // 151552 B

    const int tid  = threadIdx.x;
    const int lane = tid & 63;
    const int w    = tid >> 6;             // wave 0..7
    const int quad = lane >> 4;
    const int nc   = lane & 15;
    const int r0   = blockIdx.x << 4;
    const int c0   = (w << 4) + nc;
    const int c1   = 128 + c0;
    const float4 bc0 = bcp[c0];
    const float4 bc1 = bcp[c1];
    const float  bl  = b_lin[c0];          // y col == c0
    const uint4* wcw0 = wc + (size_t)w * 2048;        // 32 tiles * 64
    const uint4* wcw1 = wc + (size_t)(w + 8) * 2048;

    // ---- AGPR-pinned tiles: kt0-3 of all 8 gate groups
    half8 pr0[4], pz0[4], pi0[4], ph0[4], pr1[4], pz1[4], pi1[4], ph1[4];
    #pragma unroll
    for (int kt = 0; kt < 4; ++kt) {
        pr0[kt] = ld_agpr(&wcw0[kt * 64 + lane]);
        pz0[kt] = ld_agpr(&wcw0[(8 + kt) * 64 + lane]);
        pi0[kt] = ld_agpr(&wcw0[(16 + kt) * 64 + lane]);
        ph0[kt] = ld_agpr(&wcw0[(24 + kt) * 64 + lane]);
        pr1[kt] = ld_agpr(&wcw1[kt * 64 + lane]);
        pz1[kt] = ld_agpr(&wcw1[(8 + kt) * 64 + lane]);
        pi1[kt] = ld_agpr(&wcw1[(16 + kt) * 64 + lane]);
        ph1[kt] = ld_agpr(&wcw1[(24 + kt) * 64 + lane]);
    }

    // ---- LDS-resident tiles: r0 kt4-7, r1 kt4-7, y kt0-7
    const int wbase = 1280 + (w << 10);
    #pragma unroll
    for (int i = 0; i < 4; ++i) {
        lds[wbase + (i << 6) + lane]       = wcw0[(4 + i) * 64 + lane];
        lds[wbase + ((4 + i) << 6) + lane] = wcw1[(4 + i) * 64 + lane];
    }
    #pragma unroll
    for (int i = 0; i < 8; ++i)
        lds[wbase + ((8 + i) << 6) + lane] = wl[(size_t)(w * 8 + i) * 64 + lane];

    // fp32 master hidden state: rows quad*4+d; [0..3]=c0, [4..7]=c1
    float hreg[8];
    #pragma unroll
    for (int d = 0; d < 4; ++d) {
        hreg[d]     = hidden[(r0 + (quad << 2) + d) * 256 + c0];
        hreg[4 + d] = hidden[(r0 + (quad << 2) + d) * 256 + c1];
    }

    // A-frag write addressing: A[m][k]: kt=k>>5, k'=k&31,
    // frag lane=(k'>>3)*16+m, j=k'&7; u16 idx=(kt*64+lane_f)*8+j
    unsigned short* lds_u16 = (unsigned short*)lds;
    const int kp  = ((w & 1) << 4) + nc;
    const int lf  = ((kp >> 3) << 4) + (quad << 2);
    const int hfb0 = (((w >> 1) * 64 + lf) << 3) + (kp & 7);
    const int hfb1 = (((4 + (w >> 1)) * 64 + lf) << 3) + (kp & 7);

    // init h(0) frags -> buf0
    for (int idx = tid; idx < 2048; idx += 512) {
        int ktl = idx >> 8;
        int rem = idx & 255;
        int lfr = rem >> 2, jg = rem & 3;
        int m = lfr & 15;
        int hc = ktl * 32 + (lfr >> 4) * 8 + jg * 2;
        const float* p = hidden + (r0 + m) * 256 + hc;
        unsigned pk = (unsigned)f2h(p[0]) | ((unsigned)f2h(p[1]) << 16);
        ((unsigned*)lds)[(ktl * 64 + lfr) * 4 + jg] = pk;
    }
    // init x frags -> xbuf
    for (int idx = tid; idx < 1024; idx += 512) {
        int kt = idx >> 8, lfr = (idx >> 2) & 63, jg = idx & 3;
        int m = lfr & 15;
        int k0 = (kt << 5) + ((lfr >> 4) << 3) + (jg << 1);
        const float* p = inputs + (r0 + m) * 128 + k0;
        unsigned pk = (unsigned)f2h(p[0]) | ((unsigned)f2h(p[1]) << 16);
        ((unsigned*)lds)[(1024 + (kt << 6) + lfr) * 4 + jg] = pk;
    }
    __syncthreads();

    // ---- t = 0: K=384 on [x|h] with original w0 (streamed once)
    {
        #pragma unroll
        for (int g2 = 0; g2 < 2; ++g2) {
            const uint4* ww = w0 + (size_t)(g2 ? (w + 8) : w) * 2304;  // 36*64
            floatx4 ar = {0.f,0.f,0.f,0.f}, az = {0.f,0.f,0.f,0.f};
            floatx4 ain = {0.f,0.f,0.f,0.f}, ahn = {0.f,0.f,0.f,0.f};
            #pragma unroll
            for (int kt = 0; kt < 12; ++kt) {
                half8 A = as_h8(kt < 4 ? lds[1024 + (kt << 6) + lane]
                                       : lds[((kt - 4) << 6) + lane]);
                ar = MFMA16(A, as_h8(ww[kt * 64 + lane]), ar);
                az = MFMA16(A, as_h8(ww[(12 + kt) * 64 + lane]), az);
                if (kt < 4)
                    ain = MFMA16(A, as_h8(ww[(24 + kt) * 64 + lane]), ain);
                else
                    ahn = MFMA16(A, as_h8(ww[(24 + kt) * 64 + lane]), ahn);
            }
            const int cc = g2 ? c1 : c0;
            const int hfb = g2 ? hfb1 : hfb0;
            float4 b0 = bias0[cc];
            #pragma unroll
            for (int d = 0; d < 4; ++d) {
                float rr = sigm(ar[d] + b0.x);
                float zz = sigm(az[d] + b0.y);
                float nn = tanh_fast(ain[d] + b0.z + rr * (ahn[d] + b0.w));
                float hnew = (1.0f - zz) * nn + zz * hreg[(g2 << 2) + d];
                hreg[(g2 << 2) + d] = hnew;
                lds_u16[4096 + hfb + (d << 3)] = f2h(hnew);   // buf1
            }
        }
        bar_lgkm();
    }

    for (int t = 1; t < 256; ++t) {
        const int rb   = (t & 1) << 9;                 // read buf (uint4)
        const int wb16 = (((t + 1) & 1) << 9) << 3;    // write buf (u16)

        // opaque per-iteration pointers: streamed tiles cannot be hoisted
        const uint4* s0p = wcw0 + lane;
        const uint4* s1p = wcw1 + lane;
        asm("" : "+v"(s0p), "+v"(s1p));

        // streamed tiles: z/in/hn kt4-7, batch for kt issued >=1 iter early,
        // first consumer is kt=4 -> >=4 iterations of L2-latency cover.
        uint4 sz0[4], si0[4], sh0[4], sz1[4], si1[4], sh1[4];
        sz0[0] = s0p[12 * 64]; si0[0] = s0p[20 * 64]; sh0[0] = s0p[28 * 64];
        sz1[0] = s1p[12 * 64]; si1[0] = s1p[20 * 64]; sh1[0] = s1p[28 * 64];

        floatx4 acr0 = {0.f,0.f,0.f,0.f}, acz0 = {0.f,0.f,0.f,0.f};
        floatx4 aci0 = {0.f,0.f,0.f,0.f}, ach0 = {0.f,0.f,0.f,0.f};
        floatx4 acr1 = {0.f,0.f,0.f,0.f}, acz1 = {0.f,0.f,0.f,0.f};
        floatx4 aci1 = {0.f,0.f,0.f,0.f}, ach1 = {0.f,0.f,0.f,0.f};

        #pragma unroll
        for (int kt = 0; kt < 4; ++kt) {               // B from AGPR pins
            half8 A = as_h8(lds[rb + (kt << 6) + lane]);
            if (kt == 1) {
                sz0[1] = s0p[13 * 64]; si0[1] = s0p[21 * 64]; sh0[1] = s0p[29 * 64];
                sz1[1] = s1p[13 * 64]; si1[1] = s1p[21 * 64]; sh1[1] = s1p[29 * 64];
            }
            if (kt == 2) {
                sz0[2] = s0p[14 * 64]; si0[2] = s0p[22 * 64]; sh0[2] = s0p[30 * 64];
                sz1[2] = s1p[14 * 64]; si1[2] = s1p[22 * 64]; sh1[2] = s1p[30 * 64];
            }
            if (kt == 3) {
                sz0[3] = s0p[15 * 64]; si0[3] = s0p[23 * 64]; sh0[3] = s0p[31 * 64];
                sz1[3] = s1p[15 * 64]; si1[3] = s1p[23 * 64]; sh1[3] = s1p[31 * 64];
            }
            acr0 = MFMA16(A, pr0[kt], acr0);
            acr1 = MFMA16(A, pr1[kt], acr1);
            acz0 = MFMA16(A, pz0[kt], acz0);
            acz1 = MFMA16(A, pz1[kt], acz1);
            aci0 = MFMA16(A, pi0[kt], aci0);
            aci1 = MFMA16(A, pi1[kt], aci1);
            ach0 = MFMA16(A, ph0[kt], ach0);
            ach1 = MFMA16(A, ph1[kt], ach1);
        }
        #pragma unroll
        for (int kt = 0; kt < 4; ++kt) {               // kt+4: r from LDS, rest streamed
            half8 A = as_h8(lds[rb + ((4 + kt) << 6) + lane]);
            acr0 = MFMA16(A, as_h8(lds[wbase + (kt << 6) + lane]), acr0);
            acr1 = MFMA16(A, as_h8(lds[wbase + ((4 + kt) << 6) + lane]), acr1);
            acz0 = MFMA16(A, as_h8(sz0[kt]), acz0);
            acz1 = MFMA16(A, as_h8(sz1[kt]), acz1);
            aci0 = MFMA16(A, as_h8(si0[kt]), aci0);
            aci1 = MFMA16(A, as_h8(si1[kt]), aci1);
            ach0 = MFMA16(A, as_h8(sh0[kt]), ach0);
            ach1 = MFMA16(A, as_h8(sh1[kt]), ach1);
        }

        // gate epilogue -> h(t+1) frags into write buffer
        #pragma unroll
        for (int d = 0; d < 4; ++d) {
            float rr = sigm(acr0[d] + bc0.x);
            float zz = sigm(acz0[d] + bc0.y);
            float nn = tanh_fast(aci0[d] + bc0.z + rr * (ach0[d] + bc0.w));
            float hnew = (1.0f - zz) * nn + zz * hreg[d];
            hreg[d] = hnew;
            lds_u16[wb16 + hfb0 + (d << 3)] = f2h(hnew);
        }
        #pragma unroll
        for (int d = 0; d < 4; ++d) {
            float rr = sigm(acr1[d] + bc1.x);
            float zz = sigm(acz1[d] + bc1.y);
            float nn = tanh_fast(aci1[d] + bc1.z + rr * (ach1[d] + bc1.w));
            float hnew = (1.0f - zz) * nn + zz * hreg[4 + d];
            hreg[4 + d] = hnew;
            lds_u16[wb16 + hfb1 + (d << 3)] = f2h(hnew);
        }

        // fused y-GEMM: y[t-1] = h(t) @ W_lin^T + b_lin (h(t) frags = buf[rb]).
        // Two accumulator chains (4-deep each); plain stores, no atomics.
        {
            floatx4 acy0 = {0.f,0.f,0.f,0.f}, acy1 = {0.f,0.f,0.f,0.f};
            #pragma unroll
            for (int kt = 0; kt < 4; ++kt) {
                half8 A0 = as_h8(lds[rb + (kt << 6) + lane]);
                half8 A1 = as_h8(lds[rb + ((4 + kt) << 6) + lane]);
                acy0 = MFMA16(A0, as_h8(lds[wbase + ((8 + kt) << 6) + lane]), acy0);
                acy1 = MFMA16(A1, as_h8(lds[wbase + ((12 + kt) << 6) + lane]), acy1);
            }
            float* orow = out + ((size_t)(t - 1) * 1024 + r0 + (quad << 2)) * 128 + c0;
            #pragma unroll
            for (int d = 0; d < 4; ++d)
                orow[(size_t)d << 7] = acy0[d] + acy1[d] + bl;
        }
        bar_lgkm();
    }

    // final y for t=255: h(256) frags are in buf0
    {
        floatx4 acy0 = {0.f,0.f,0.f,0.f}, acy1 = {0.f,0.f,0.f,0.f};
        #pragma unroll
        for (int kt = 0; kt < 4; ++kt) {
            half8 A0 = as_h8(lds[(kt << 6) + lane]);
            half8 A1 = as_h8(lds[((4 + kt) << 6) + lane]);
            acy0 = MFMA16(A0, as_h8(lds[wbase + ((8 + kt) << 6) + lane]), acy0);
            acy1 = MFMA16(A1, as_h8(lds[wbase + ((12 + kt) << 6) + lane]), acy1);
        }
        float* orow = out + ((size_t)255 * 1024 + r0 + (quad << 2)) * 128 + c0;
        #pragma unroll
        for (int d = 0; d < 4; ++d)
            orow[(size_t)d << 7] = acy0[d] + acy1[d] + bl;
    }
}

// ---------------------------------------------------------------------------
// BN stats: one block per timestep t. Coalesced float4 sweep of out[t]
// (1024 x 128), wave shfl + LDS reduce, writes {mean, rsqrt(var+eps)}.
// ---------------------------------------------------------------------------
__global__ __launch_bounds__(256) void stats_kernel(const float* __restrict__ out,
                                                    float2* __restrict__ stats)
{
    __shared__ float sh[4][32][8];
    const int tid = threadIdx.x;
    const int t = blockIdx.x;
    const int fc = tid & 31;               // float4 column (channels 4fc..4fc+3)
    const int rb = tid >> 5;               // row phase 0..7
    const float4* base = (const float4*)(out + (size_t)t * 131072);

    float4 s1 = make_float4(0.f, 0.f, 0.f, 0.f);
    float4 s2 = make_float4(0.f, 0.f, 0.f, 0.f);
    #pragma unroll 4
    for (int r = rb; r < 1024; r += 8) {
        float4 v = base[r * 32 + fc];
        s1.x += v.x; s1.y += v.y; s1.z += v.z; s1.w += v.w;
        s2.x += v.x * v.x; s2.y += v.y * v.y;
        s2.z += v.z * v.z; s2.w += v.w * v.w;
    }
    // lanes l and l^32 share fc -> reduce within wave
    s1.x += __shfl_xor(s1.x, 32); s1.y += __shfl_xor(s1.y, 32);
    s1.z += __shfl_xor(s1.z, 32); s1.w += __shfl_xor(s1.w, 32);
    s2.x += __shfl_xor(s2.x, 32); s2.y += __shfl_xor(s2.y, 32);
    s2.z += __shfl_xor(s2.z, 32); s2.w += __shfl_xor(s2.w, 32);
    const int lane = tid & 63, wv = tid >> 6;
    if (lane < 32) {
        sh[wv][lane][0] = s1.x; sh[wv][lane][1] = s1.y;
        sh[wv][lane][2] = s1.z; sh[wv][lane][3] = s1.w;
        sh[wv][lane][4] = s2.x; sh[wv][lane][5] = s2.y;
        sh[wv][lane][6] = s2.z; sh[wv][lane][7] = s2.w;
    }
    __syncthreads();
    if (tid < 32) {
        float a1[4] = {0.f, 0.f, 0.f, 0.f}, a2[4] = {0.f, 0.f, 0.f, 0.f};
        #pragma unroll
        for (int k = 0; k < 4; ++k) {
            #pragma unroll
            for (int j = 0; j < 4; ++j) {
                a1[j] += sh[k][tid][j];
                a2[j] += sh[k][tid][4 + j];
            }
        }
        #pragma unroll
        for (int j = 0; j < 4; ++j) {
            float mean = a1[j] * (1.0f / 1024.0f);
            float var  = a2[j] * (1.0f / 1024.0f) - mean * mean;
            stats[t * 128 + tid * 4 + j] = make_float2(mean, rsqrtf(var + EPS_BN));
        }
    }
}

// ---------------------------------------------------------------------------
// Normalize: in-place BN applying precomputed {mean, scale}.
// ---------------------------------------------------------------------------
__global__ void norm_kernel(float* __restrict__ out, const float2* __restrict__ stats)
{
    __shared__ float smean[128], sscale[128];
    int t = blockIdx.x >> 2, q = blockIdx.x & 3;
    int tid = threadIdx.x;
    if (tid < 128) {
        float2 ms = stats[t * 128 + tid];
        smean[tid] = ms.x;
        sscale[tid] = ms.y;
    }
    __syncthreads();
    float4* p = (float4*)(out + ((size_t)t << 17) + ((size_t)q << 15));
    for (int i = tid; i < 8192; i += 256) {
        int cc = (i & 31) << 2;
        float4 v = p[i];
        v.x = (v.x - smean[cc])     * sscale[cc];
        v.y = (v.y - smean[cc + 1]) * sscale[cc + 1];
        v.z = (v.z - smean[cc + 2]) * sscale[cc + 2];
        v.w = (v.w - smean[cc + 3]) * sscale[cc + 3];
        p[i] = v;
    }
}

extern "C" void kernel_launch(void* const* d_in, const int* in_sizes, int n_in,
                              void* d_out, int out_size, void* d_ws, size_t ws_size,
                              hipStream_t stream) {
    (void)in_sizes; (void)n_in; (void)out_size; (void)ws_size;
    const float* inputs = (const float*)d_in[0];
    const float* hidden = (const float*)d_in[1];
    const float* W_ih   = (const float*)d_in[2];
    const float* b_ih   = (const float*)d_in[3];
    const float* W_hh   = (const float*)d_in[4];
    const float* b_hh   = (const float*)d_in[5];
    const float* W_lin  = (const float*)d_in[6];
    const float* b_lin  = (const float*)d_in[7];

    char* ws = (char*)d_ws;
    uint4*  wcp   = (uint4*)(ws + WS_WC);
    uint4*  w0p   = (uint4*)(ws + WS_W0);
    uint4*  wlp   = (uint4*)(ws + WS_WL);
    float4* bias0 = (float4*)(ws + WS_B0);
    float4* bcp   = (float4*)(ws + WS_BC);
    float2* stats = (float2*)(ws + WS_ST);

    pack_w0_kernel<<<161, 256, 0, stream>>>(W_ih, W_hh, W_lin, b_ih, b_hh, w0p, wlp, bias0);
    pack_wc_kernel<<<129, 256, 0, stream>>>(W_ih, W_hh, W_lin, b_ih, b_hh, b_lin, wcp, bcp);
    gru_kernel<<<64, 512, 0, stream>>>(inputs, hidden, wcp, w0p, wlp, bias0, bcp, b_lin,
                                       (float*)d_out);
    stats_kernel<<<256, 256, 0, stream>>>((const float*)d_out, stats);
    norm_kernel<<<1024, 256, 0, stream>>>((float*)d_out, stats);
}

// Round 3
// 1047.336 us; speedup vs baseline: 1.4395x; 1.3380x over previous
//
#include <hip/hip_runtime.h>

// ---------------------------------------------------------------------------
// GRU (T=256, B=1024, IN=128, H=256) + per-step BatchNorm, MI355X.
// R8->R9: revert to the R6 structure (register-feasible: 128 VGPR + 128 AGPR
// = exactly the 256/wave budget at 8 waves/CU). R7/R8's remap needed 96 live
// streamed VGPRs -> allocator serialized the loads -> exposed L2 latency
// (VALUBusy fell 14.7->6.5 while time rose). Kept deltas, all register-neutral:
//   (1) fast rcp/exp2 activations (kills 24 div sequences/thread/step)
//   (2) lgkm-only barrier (global u16 h-stores don't drain per step)
//   (3) streamed-lead remap: LDS holds in/hn kt0-3, streamed in/hn kt4-7
//       (first streamed use kt=4 instead of kt=0; same 16 live uint4 peak)
// ygemm/norm/pack are R6 verbatim.
// ---------------------------------------------------------------------------

typedef _Float16 half8 __attribute__((ext_vector_type(8)));
typedef float floatx4 __attribute__((ext_vector_type(4)));
typedef unsigned uintx4 __attribute__((ext_vector_type(4)));

#define EPS_BN 1e-5f

// ws layout (bytes):
//   [0,       524288)   wc: folded gate weights, 16 cgs x 32 tiles x 1 KB
//   [524288, 1114112)   w0: step-0 weights, 16 cgs x 36 tiles x 1 KB
//   [1114112,1179648)   wl: W_lin B-frags, 64 tiles x 1 KB
//   [1179648,1183744)   bias0: 256 x float4
//   [1183744,1187840)   bc: 256 x float4 folded biases
//   [1187840,1449984)   stats: 256 t x 128 c x {sum,sumsq} fp32 (memset 0)
#define WS_WC 0
#define WS_W0 524288
#define WS_WL 1114112
#define WS_B0 1179648
#define WS_BC 1183744
#define WS_ST 1187840

static __device__ __forceinline__ unsigned short f2h(float f) {
    union { _Float16 h; unsigned short u; } v;
    v.h = (_Float16)f;                      // v_cvt_f16_f32, RNE
    return v.u;
}
static __device__ __forceinline__ half8 as_h8(uint4 v) {
    union { uint4 u; half8 h; } x; x.u = v; return x.h;
}
// Load a 16B weight fragment and force it into AGPRs (opaque, non-remat).
static __device__ __forceinline__ half8 ld_agpr(const uint4* p) {
    uintx4 v = *(const uintx4*)p;
    asm volatile("; wpin" : "+a"(v));
    union { uintx4 u; half8 h; } x; x.u = v; return x.h;
}
// Fast activations: v_rcp_f32 + v_exp_f32 (1 ulp each) instead of the
// ~10-instr correctly-rounded f32 divide sequence hipcc emits for 1.0f/x.
static __device__ __forceinline__ float sigm(float x) {
    return __builtin_amdgcn_rcpf(1.0f + __builtin_amdgcn_exp2f(-1.442695041f * x));
}
static __device__ __forceinline__ float tanh_fast(float x) {
    return 1.0f - 2.0f * __builtin_amdgcn_rcpf(1.0f + __builtin_amdgcn_exp2f(2.885390082f * x));
}
// Workgroup barrier that drains LDS only (no vmcnt(0) store-drain). Safe:
// cross-wave data exchange is exclusively through LDS; the global u16
// h-stores are only read by ygemm_kernel after this kernel completes.
static __device__ __forceinline__ void bar_lgkm() {
    asm volatile("s_waitcnt lgkmcnt(0)\n\ts_barrier" ::: "memory");
}
#define MFMA16(A, B, C) __builtin_amdgcn_mfma_f32_16x16x32_f16((A), (B), (C), 0, 0, 0)

// ---------------------------------------------------------------------------
// pack_w0: original weights -> fp16 B-frag tiles + wl + bias0. (R3-verified)
// B-frag 16x16x32: lane l holds B[n0+(l&15)][k0+(l>>4)*8+j].
// ---------------------------------------------------------------------------
__global__ void pack_w0_kernel(const float* __restrict__ W_ih, const float* __restrict__ W_hh,
                               const float* __restrict__ W_lin, const float* __restrict__ b_ih,
                               const float* __restrict__ b_hh,
                               uint4* __restrict__ w0, uint4* __restrict__ wl,
                               float4* __restrict__ bias0)
{
    int i = blockIdx.x * 256 + threadIdx.x;
    if (i < 36864) {                       // 576 w0 tiles x 64 lanes
        int lane = i & 63, tile = i >> 6;
        int w = tile / 36, rem = tile - w * 36;
        int g = rem / 12, kt = rem - g * 12;
        int n = g * 256 + (w << 4) + (lane & 15);
        int k0 = (kt << 5) + ((lane >> 4) << 3);
        const float* p = (k0 < 128) ? (W_ih + n * 128 + k0)
                                    : (W_hh + n * 256 + (k0 - 128));
        unsigned short h[8];
        #pragma unroll
        for (int j = 0; j < 8; ++j) h[j] = f2h(p[j]);
        uint4 v;
        v.x = (unsigned)h[0] | ((unsigned)h[1] << 16);
        v.y = (unsigned)h[2] | ((unsigned)h[3] << 16);
        v.z = (unsigned)h[4] | ((unsigned)h[5] << 16);
        v.w = (unsigned)h[6] | ((unsigned)h[7] << 16);
        w0[i] = v;
    } else if (i < 40960) {                // 64 wl tiles x 64 lanes
        int i2 = i - 36864;
        int lane = i2 & 63, tile = i2 >> 6;        // tile = nt*8 + kt
        int n = (tile >> 3) * 16 + (lane & 15);
        int k0 = ((tile & 7) << 5) + ((lane >> 4) << 3);
        const float* p = W_lin + n * 256 + k0;
        unsigned short h[8];
        #pragma unroll
        for (int j = 0; j < 8; ++j) h[j] = f2h(p[j]);
        uint4 v;
        v.x = (unsigned)h[0] | ((unsigned)h[1] << 16);
        v.y = (unsigned)h[2] | ((unsigned)h[3] << 16);
        v.z = (unsigned)h[4] | ((unsigned)h[5] << 16);
        v.w = (unsigned)h[6] | ((unsigned)h[7] << 16);
        wl[i2] = v;
    } else if (i < 41216) {
        int cb = i - 40960;
        bias0[cb] = make_float4(b_ih[cb] + b_hh[cb],
                                b_ih[256 + cb] + b_hh[256 + cb],
                                b_ih[512 + cb], b_hh[512 + cb]);
    }
}

// ---------------------------------------------------------------------------
// pack_wc: folded weights (fp32 fold, one fp16 round) + folded biases.
// tile idx = cg*32 + g*8 + kt; g: 0=r (W_ih_r@W_lin + W_hh_r), 1=z,
// 2=in (W_ihn@W_lin), 3=hn (W_hhn). (R5-verified)
// ---------------------------------------------------------------------------
__global__ void pack_wc_kernel(const float* __restrict__ W_ih, const float* __restrict__ W_hh,
                               const float* __restrict__ W_lin, const float* __restrict__ b_ih,
                               const float* __restrict__ b_hh, const float* __restrict__ b_lin,
                               uint4* __restrict__ wc, float4* __restrict__ bc)
{
    int i = blockIdx.x * 256 + threadIdx.x;
    if (i < 32768) {                       // 512 wc tiles x 64 lanes
        int lane = i & 63, tile = i >> 6;
        int w = tile >> 5, r = tile & 31;
        int g = r >> 3, kt = r & 7;
        int c = (w << 4) + (lane & 15);
        int k0 = (kt << 5) + ((lane >> 4) << 3);
        float s[8];
        if (g == 3) {
            #pragma unroll
            for (int j = 0; j < 8; ++j) s[j] = W_hh[(512 + c) * 256 + k0 + j];
        } else {
            int row = g * 256 + c;
            const float* wi = W_ih + row * 128;
            #pragma unroll
            for (int j = 0; j < 8; ++j) s[j] = 0.0f;
            for (int ii = 0; ii < 128; ++ii) {
                float wv = wi[ii];
                const float* wrow = W_lin + ii * 256 + k0;
                #pragma unroll
                for (int j = 0; j < 8; ++j) s[j] += wv * wrow[j];
            }
            if (g < 2) {
                #pragma unroll
                for (int j = 0; j < 8; ++j) s[j] += W_hh[row * 256 + k0 + j];
            }
        }
        unsigned short h[8];
        #pragma unroll
        for (int j = 0; j < 8; ++j) h[j] = f2h(s[j]);
        uint4 v;
        v.x = (unsigned)h[0] | ((unsigned)h[1] << 16);
        v.y = (unsigned)h[2] | ((unsigned)h[3] << 16);
        v.z = (unsigned)h[4] | ((unsigned)h[5] << 16);
        v.w = (unsigned)h[6] | ((unsigned)h[7] << 16);
        wc[i] = v;
    } else if (i < 33024) {
        int c = i - 32768;
        float d0 = 0.f, d1 = 0.f, d2 = 0.f;
        for (int ii = 0; ii < 128; ++ii) {
            float bl = b_lin[ii];
            d0 += bl * W_ih[c * 128 + ii];
            d1 += bl * W_ih[(256 + c) * 128 + ii];
            d2 += bl * W_ih[(512 + c) * 128 + ii];
        }
        bc[c] = make_float4(b_ih[c] + b_hh[c] + d0,
                            b_ih[256 + c] + b_hh[256 + c] + d1,
                            b_ih[512 + c] + d2,
                            b_hh[512 + c]);
    }
}

// ---------------------------------------------------------------------------
// Recurrence: 64 blocks x 512 thr (8 waves, 2/SIMD). Block owns 16 batch
// rows; wave w owns col-groups {w, w+8} (cols c0=w*16.., c1=128+w*16..).
// Residency per wave (64 gate tiles):
//   AGPR 32: r kt0-7, z kt0-7, both col-groups   (128 AGPRs, asm "+a" pinned)
//   LDS  16: in kt0-3, hn kt0-3, both col-groups (first-used kt<4)
//   streamed 16/step: in kt4-7, hn kt4-7 (first use kt=4 -> >=4-iter lead;
//       peak 16 live uint4 = 64 VGPRs, same as R6)
// LDS (uint4): [0,1024) h-frag dbuf | [1024,1280) xbuf | [1280,9472)
// per-wave weight tiles (16/wave). One lgkm-only barrier per step.
// ---------------------------------------------------------------------------
__global__ __launch_bounds__(512, 2) void gru_kernel(
    const float* __restrict__ inputs,
    const float* __restrict__ hidden,
    const uint4* __restrict__ wc,
    const uint4* __restrict__ w0,
    const float4* __restrict__ bias0,
    const float4* __restrict__ bcp,
    float* __restrict__ out)
{
    __shared__ uint4 lds[9472];            // 151552 B

    const int tid  = threadIdx.x;
    const int lane = tid & 63;
    const int w    = tid >> 6;             // wave 0..7
    const int quad = lane >> 4;
    const int nc   = lane & 15;
    const int r0   = blockIdx.x << 4;
    const int c0   = (w << 4) + nc;
    const int c1   = 128 + c0;
    const float4 bc0 = bcp[c0];
    const float4 bc1 = bcp[c1];
    const uint4* wcw0 = wc + (size_t)w * 2048;        // 32 tiles * 64
    const uint4* wcw1 = wc + (size_t)(w + 8) * 2048;

    // ---- AGPR-pinned tiles: r kt0-7, z kt0-7 for both col-groups
    half8 wr0[8], wz0[8], wr1[8], wz1[8];
    #pragma unroll
    for (int kt = 0; kt < 8; ++kt) {
        wr0[kt] = ld_agpr(&wcw0[kt * 64 + lane]);
        wz0[kt] = ld_agpr(&wcw0[(8 + kt) * 64 + lane]);
        wr1[kt] = ld_agpr(&wcw1[kt * 64 + lane]);
        wz1[kt] = ld_agpr(&wcw1[(8 + kt) * 64 + lane]);
    }

    // ---- LDS-resident tiles: in kt0-3 (tiles 16-19), hn kt0-3 (tiles 24-27)
    // slot layout per cg: [0-3]=in kt0-3, [4-7]=hn kt0-3; cg1 at +512.
    const int wbase = 1280 + (w << 10);
    #pragma unroll
    for (int i = 0; i < 4; ++i) {
        lds[wbase + (i << 6) + lane]             = wcw0[(16 + i) * 64 + lane];
        lds[wbase + ((4 + i) << 6) + lane]       = wcw0[(24 + i) * 64 + lane];
        lds[wbase + 512 + (i << 6) + lane]       = wcw1[(16 + i) * 64 + lane];
        lds[wbase + 512 + ((4 + i) << 6) + lane] = wcw1[(24 + i) * 64 + lane];
    }

    // fp32 master hidden state: rows quad*4+d; [0..3]=c0, [4..7]=c1
    float hreg[8];
    #pragma unroll
    for (int d = 0; d < 4; ++d) {
        hreg[d]     = hidden[(r0 + (quad << 2) + d) * 256 + c0];
        hreg[4 + d] = hidden[(r0 + (quad << 2) + d) * 256 + c1];
    }

    // A-frag write addressing: A[m][k]: kt=k>>5, k'=k&31,
    // frag lane=(k'>>3)*16+m, j=k'&7; u16 idx=(kt*64+lane_f)*8+j
    unsigned short* lds_u16 = (unsigned short*)lds;
    const int kp  = ((w & 1) << 4) + nc;
    const int lf  = ((kp >> 3) << 4) + (quad << 2);
    const int hfb0 = (((w >> 1) * 64 + lf) << 3) + (kp & 7);
    const int hfb1 = (((4 + (w >> 1)) * 64 + lf) << 3) + (kp & 7);

    // init h(0) frags -> buf0
    for (int idx = tid; idx < 2048; idx += 512) {
        int ktl = idx >> 8;
        int rem = idx & 255;
        int lfr = rem >> 2, jg = rem & 3;
        int m = lfr & 15;
        int hc = ktl * 32 + (lfr >> 4) * 8 + jg * 2;
        const float* p = hidden + (r0 + m) * 256 + hc;
        unsigned pk = (unsigned)f2h(p[0]) | ((unsigned)f2h(p[1]) << 16);
        ((unsigned*)lds)[(ktl * 64 + lfr) * 4 + jg] = pk;
    }
    // init x frags -> xbuf
    for (int idx = tid; idx < 1024; idx += 512) {
        int kt = idx >> 8, lfr = (idx >> 2) & 63, jg = idx & 3;
        int m = lfr & 15;
        int k0 = (kt << 5) + ((lfr >> 4) << 3) + (jg << 1);
        const float* p = inputs + (r0 + m) * 128 + k0;
        unsigned pk = (unsigned)f2h(p[0]) | ((unsigned)f2h(p[1]) << 16);
        ((unsigned*)lds)[(1024 + (kt << 6) + lfr) * 4 + jg] = pk;
    }
    __syncthreads();

    unsigned short* Hout = (unsigned short*)out;

    // ---- t = 0: K=384 on [x|h] with original w0 (streamed once)
    {
        #pragma unroll
        for (int g2 = 0; g2 < 2; ++g2) {
            const uint4* ww = w0 + (size_t)(g2 ? (w + 8) : w) * 2304;  // 36*64
            floatx4 ar = {0.f,0.f,0.f,0.f}, az = {0.f,0.f,0.f,0.f};
            floatx4 ain = {0.f,0.f,0.f,0.f}, ahn = {0.f,0.f,0.f,0.f};
            #pragma unroll
            for (int kt = 0; kt < 12; ++kt) {
                half8 A = as_h8(kt < 4 ? lds[1024 + (kt << 6) + lane]
                                       : lds[((kt - 4) << 6) + lane]);
                ar = MFMA16(A, as_h8(ww[kt * 64 + lane]), ar);
                az = MFMA16(A, as_h8(ww[(12 + kt) * 64 + lane]), az);
                if (kt < 4)
                    ain = MFMA16(A, as_h8(ww[(24 + kt) * 64 + lane]), ain);
                else
                    ahn = MFMA16(A, as_h8(ww[(24 + kt) * 64 + lane]), ahn);
            }
            const int cc = g2 ? c1 : c0;
            const int hfb = g2 ? hfb1 : hfb0;
            float4 b0 = bias0[cc];
            #pragma unroll
            for (int d = 0; d < 4; ++d) {
                float rr = sigm(ar[d] + b0.x);
                float zz = sigm(az[d] + b0.y);
                float nn = tanh_fast(ain[d] + b0.z + rr * (ahn[d] + b0.w));
                float hnew = (1.0f - zz) * nn + zz * hreg[(g2 << 2) + d];
                hreg[(g2 << 2) + d] = hnew;
                unsigned short hu = f2h(hnew);
                lds_u16[4096 + hfb + (d << 3)] = hu;      // buf1
                Hout[((size_t)(r0 + (quad << 2) + d) << 8) + cc] = hu;
            }
        }
        bar_lgkm();
    }

    for (int t = 1; t < 256; ++t) {
        const int rb   = (t & 1) << 9;                 // read buf (uint4)
        const int wb16 = (((t + 1) & 1) << 9) << 3;    // write buf (u16)

        // opaque per-iteration pointers: streamed tiles cannot be hoisted
        const uint4* s0p = wcw0 + lane;
        const uint4* s1p = wcw1 + lane;
        asm("" : "+v"(s0p), "+v"(s1p));

        // streamed tiles: in kt4-7 (tiles 20-23), hn kt4-7 (tiles 28-31).
        // Batches at top and kt=1,2,3; first consumer kt=4 -> >=4-iter lead.
        uint4 si0[4], sh0[4], si1[4], sh1[4];
        si0[0] = s0p[20 * 64]; sh0[0] = s0p[28 * 64];
        si1[0] = s1p[20 * 64]; sh1[0] = s1p[28 * 64];

        floatx4 ar0 = {0.f,0.f,0.f,0.f}, az0 = {0.f,0.f,0.f,0.f};
        floatx4 ai0 = {0.f,0.f,0.f,0.f}, ah0 = {0.f,0.f,0.f,0.f};
        floatx4 ar1 = {0.f,0.f,0.f,0.f}, az1 = {0.f,0.f,0.f,0.f};
        floatx4 ai1 = {0.f,0.f,0.f,0.f}, ah1 = {0.f,0.f,0.f,0.f};

        #pragma unroll
        for (int kt = 0; kt < 8; ++kt) {
            half8 A = as_h8(lds[rb + (kt << 6) + lane]);
            if (kt == 1) {
                si0[1] = s0p[21 * 64]; sh0[1] = s0p[29 * 64];
                si1[1] = s1p[21 * 64]; sh1[1] = s1p[29 * 64];
            }
            if (kt == 2) {
                si0[2] = s0p[22 * 64]; sh0[2] = s0p[30 * 64];
                si1[2] = s1p[22 * 64]; sh1[2] = s1p[30 * 64];
            }
            if (kt == 3) {
                si0[3] = s0p[23 * 64]; sh0[3] = s0p[31 * 64];
                si1[3] = s1p[23 * 64]; sh1[3] = s1p[31 * 64];
            }
            ar0 = MFMA16(A, wr0[kt], ar0);
            ar1 = MFMA16(A, wr1[kt], ar1);
            az0 = MFMA16(A, wz0[kt], az0);
            az1 = MFMA16(A, wz1[kt], az1);
            half8 Bi0 = (kt < 4) ? as_h8(lds[wbase + (kt << 6) + lane])
                                 : as_h8(si0[kt - 4]);
            half8 Bi1 = (kt < 4) ? as_h8(lds[wbase + 512 + (kt << 6) + lane])
                                 : as_h8(si1[kt - 4]);
            ai0 = MFMA16(A, Bi0, ai0);
            ai1 = MFMA16(A, Bi1, ai1);
            half8 Bh0 = (kt < 4) ? as_h8(lds[wbase + ((4 + kt) << 6) + lane])
                                 : as_h8(sh0[kt - 4]);
            half8 Bh1 = (kt < 4) ? as_h8(lds[wbase + 512 + ((4 + kt) << 6) + lane])
                                 : as_h8(sh1[kt - 4]);
            ah0 = MFMA16(A, Bh0, ah0);
            ah1 = MFMA16(A, Bh1, ah1);
        }

        const size_t obase = (size_t)t * 1024 + r0 + (quad << 2);
        #pragma unroll
        for (int d = 0; d < 4; ++d) {
            float rr = sigm(ar0[d] + bc0.x);
            float zz = sigm(az0[d] + bc0.y);
            float nn = tanh_fast(ai0[d] + bc0.z + rr * (ah0[d] + bc0.w));
            float hnew = (1.0f - zz) * nn + zz * hreg[d];
            hreg[d] = hnew;
            unsigned short hu = f2h(hnew);
            lds_u16[wb16 + hfb0 + (d << 3)] = hu;
            Hout[((obase + d) << 8) + c0] = hu;
        }
        #pragma unroll
        for (int d = 0; d < 4; ++d) {
            float rr = sigm(ar1[d] + bc1.x);
            float zz = sigm(az1[d] + bc1.y);
            float nn = tanh_fast(ai1[d] + bc1.z + rr * (ah1[d] + bc1.w));
            float hnew = (1.0f - zz) * nn + zz * hreg[4 + d];
            hreg[4 + d] = hnew;
            unsigned short hu = f2h(hnew);
            lds_u16[wb16 + hfb1 + (d << 3)] = hu;
            Hout[((obase + d) << 8) + c1] = hu;
        }
        bar_lgkm();
    }
}

// ---------------------------------------------------------------------------
// y-GEMM: out[t,b,:] = H[t,b,:] @ W_lin^T + b_lin, fused BN partial sums.
// In-place over d_out (stages its 16 H-rows to LDS first). (R5-verified)
// ---------------------------------------------------------------------------
__global__ __launch_bounds__(256) void ygemm_kernel(
    const uint4* __restrict__ wl, const float* __restrict__ b_lin,
    float* __restrict__ out, float* __restrict__ stats)
{
    __shared__ unsigned short sh[16 * 264];
    const int tid = threadIdx.x;
    const int t = blockIdx.x >> 6;
    const int r0 = (blockIdx.x & 63) << 4;

    {
        int row = tid >> 4, seg = tid & 15;
        const uint4* src = (const uint4*)((const unsigned short*)out
                         + (((size_t)t << 10) + r0 + row) * 256) + (seg << 1);
        uint4 a = src[0], b = src[1];
        uint4* dst = (uint4*)(sh + row * 264 + (seg << 4));
        dst[0] = a; dst[1] = b;
    }
    __syncthreads();

    const int lane = tid & 63, w = tid >> 6;
    const int quad = lane >> 4, nc = lane & 15;
    const int m = lane & 15, khi = lane >> 4;

    half8 B0[8], B1[8];
    #pragma unroll
    for (int kt = 0; kt < 8; ++kt) {
        B0[kt] = as_h8(wl[(((w << 1) + 0) * 8 + kt) * 64 + lane]);
        B1[kt] = as_h8(wl[(((w << 1) + 1) * 8 + kt) * 64 + lane]);
    }
    floatx4 a0 = {0.f,0.f,0.f,0.f}, a1 = {0.f,0.f,0.f,0.f};
    #pragma unroll
    for (int kt = 0; kt < 8; ++kt) {
        half8 A = *(const half8*)(sh + m * 264 + (kt << 5) + (khi << 3));
        a0 = MFMA16(A, B0[kt], a0);
        a1 = MFMA16(A, B1[kt], a1);
    }
    #pragma unroll
    for (int g = 0; g < 2; ++g) {
        floatx4 acc = g ? a1 : a0;
        int i = (((w << 1) + g) << 4) + nc;
        float bl = b_lin[i];
        float s1 = 0.f, s2 = 0.f;
        float* orow = out + (((size_t)t << 10) + r0 + (quad << 2)) * 128 + i;
        #pragma unroll
        for (int d = 0; d < 4; ++d) {
            float y = acc[d] + bl;
            orow[(size_t)d << 7] = y;
            s1 += y; s2 += y * y;
        }
        s1 += __shfl_xor(s1, 16); s1 += __shfl_xor(s1, 32);
        s2 += __shfl_xor(s2, 16); s2 += __shfl_xor(s2, 32);
        if (lane < 16) {
            int si = ((t << 7) + (((w << 1) + g) << 4) + lane) << 1;
            atomicAdd(&stats[si], s1);
            atomicAdd(&stats[si + 1], s2);
        }
    }
}

// ---------------------------------------------------------------------------
// Normalize: in-place BN from raw sums. Biased variance, eps inside sqrt.
// ---------------------------------------------------------------------------
__global__ void norm_kernel(float* __restrict__ out, const float* __restrict__ stats)
{
    __shared__ float smean[128], sscale[128];
    int t = blockIdx.x >> 2, q = blockIdx.x & 3;
    int tid = threadIdx.x;
    if (tid < 128) {
        int si = ((t << 7) + tid) << 1;
        float mean = stats[si] * (1.0f / 1024.0f);
        float var = stats[si + 1] * (1.0f / 1024.0f) - mean * mean;
        smean[tid] = mean;
        sscale[tid] = rsqrtf(var + EPS_BN);
    }
    __syncthreads();
    float4* p = (float4*)(out + ((size_t)t << 17) + ((size_t)q << 15));
    for (int i = tid; i < 8192; i += 256) {
        int cc = (i & 31) << 2;
        float4 v = p[i];
        v.x = (v.x - smean[cc])     * sscale[cc];
        v.y = (v.y - smean[cc + 1]) * sscale[cc + 1];
        v.z = (v.z - smean[cc + 2]) * sscale[cc + 2];
        v.w = (v.w - smean[cc + 3]) * sscale[cc + 3];
        p[i] = v;
    }
}

extern "C" void kernel_launch(void* const* d_in, const int* in_sizes, int n_in,
                              void* d_out, int out_size, void* d_ws, size_t ws_size,
                              hipStream_t stream) {
    (void)in_sizes; (void)n_in; (void)out_size; (void)ws_size;
    const float* inputs = (const float*)d_in[0];
    const float* hidden = (const float*)d_in[1];
    const float* W_ih   = (const float*)d_in[2];
    const float* b_ih   = (const float*)d_in[3];
    const float* W_hh   = (const float*)d_in[4];
    const float* b_hh   = (const float*)d_in[5];
    const float* W_lin  = (const float*)d_in[6];
    const float* b_lin  = (const float*)d_in[7];

    char* ws = (char*)d_ws;
    uint4*  wcp   = (uint4*)(ws + WS_WC);
    uint4*  w0p   = (uint4*)(ws + WS_W0);
    uint4*  wlp   = (uint4*)(ws + WS_WL);
    float4* bias0 = (float4*)(ws + WS_B0);
    float4* bcp   = (float4*)(ws + WS_BC);
    float*  stats = (float*)(ws + WS_ST);

    hipMemsetAsync(stats, 0, 262144, stream);
    pack_w0_kernel<<<161, 256, 0, stream>>>(W_ih, W_hh, W_lin, b_ih, b_hh, w0p, wlp, bias0);
    pack_wc_kernel<<<129, 256, 0, stream>>>(W_ih, W_hh, W_lin, b_ih, b_hh, b_lin, wcp, bcp);
    gru_kernel<<<64, 512, 0, stream>>>(inputs, hidden, wcp, w0p, bias0, bcp, (float*)d_out);
    ygemm_kernel<<<16384, 256, 0, stream>>>(wlp, b_lin, (float*)d_out, stats);
    norm_kernel<<<1024, 256, 0, stream>>>((float*)d_out, stats);
}

// Round 4
// 1035.287 us; speedup vs baseline: 1.4563x; 1.0116x over previous
//
#include <hip/hip_runtime.h>

// ---------------------------------------------------------------------------
// GRU (T=256, B=1024, IN=128, H=256) + per-step BatchNorm, MI355X.
// R9->R10: gru untouched (817us, proven). ygemm reworked: 32 rows/block x
// 512 thr (8192 blocks, was 16384x256): halves B-tile L2 traffic (134MB vs
// 268MB) + per-block stage overhead; cross-wave LDS combine halves the
// stats atomics (1 atomic pair per channel per block). norm/packs unchanged.
// gru structural notes (R7/R8 lessons): 512thr => 256 unified regs/wave cap;
// 128 VGPR + 128 AGPR is exactly full; any remap needing >16 live streamed
// uint4 serializes (96-VGPR wall). Fused-y impossible within budget. Grid
// capped at 64 blocks by B=1024 / M=16.
// ---------------------------------------------------------------------------

typedef _Float16 half8 __attribute__((ext_vector_type(8)));
typedef float floatx4 __attribute__((ext_vector_type(4)));
typedef unsigned uintx4 __attribute__((ext_vector_type(4)));

#define EPS_BN 1e-5f

// ws layout (bytes):
//   [0,       524288)   wc: folded gate weights, 16 cgs x 32 tiles x 1 KB
//   [524288, 1114112)   w0: step-0 weights, 16 cgs x 36 tiles x 1 KB
//   [1114112,1179648)   wl: W_lin B-frags, 64 tiles x 1 KB
//   [1179648,1183744)   bias0: 256 x float4
//   [1183744,1187840)   bc: 256 x float4 folded biases
//   [1187840,1449984)   stats: 256 t x 128 c x {sum,sumsq} fp32 (memset 0)
#define WS_WC 0
#define WS_W0 524288
#define WS_WL 1114112
#define WS_B0 1179648
#define WS_BC 1183744
#define WS_ST 1187840

static __device__ __forceinline__ unsigned short f2h(float f) {
    union { _Float16 h; unsigned short u; } v;
    v.h = (_Float16)f;                      // v_cvt_f16_f32, RNE
    return v.u;
}
static __device__ __forceinline__ half8 as_h8(uint4 v) {
    union { uint4 u; half8 h; } x; x.u = v; return x.h;
}
// Load a 16B weight fragment and force it into AGPRs (opaque, non-remat).
static __device__ __forceinline__ half8 ld_agpr(const uint4* p) {
    uintx4 v = *(const uintx4*)p;
    asm volatile("; wpin" : "+a"(v));
    union { uintx4 u; half8 h; } x; x.u = v; return x.h;
}
// Fast activations: v_rcp_f32 + v_exp_f32 (1 ulp each) instead of the
// ~10-instr correctly-rounded f32 divide sequence hipcc emits for 1.0f/x.
static __device__ __forceinline__ float sigm(float x) {
    return __builtin_amdgcn_rcpf(1.0f + __builtin_amdgcn_exp2f(-1.442695041f * x));
}
static __device__ __forceinline__ float tanh_fast(float x) {
    return 1.0f - 2.0f * __builtin_amdgcn_rcpf(1.0f + __builtin_amdgcn_exp2f(2.885390082f * x));
}
// Workgroup barrier that drains LDS only (no vmcnt(0) store-drain). Safe:
// cross-wave data exchange is exclusively through LDS; the global u16
// h-stores are only read by ygemm_kernel after this kernel completes.
static __device__ __forceinline__ void bar_lgkm() {
    asm volatile("s_waitcnt lgkmcnt(0)\n\ts_barrier" ::: "memory");
}
#define MFMA16(A, B, C) __builtin_amdgcn_mfma_f32_16x16x32_f16((A), (B), (C), 0, 0, 0)

// ---------------------------------------------------------------------------
// pack_w0: original weights -> fp16 B-frag tiles + wl + bias0. (R3-verified)
// B-frag 16x16x32: lane l holds B[n0+(l&15)][k0+(l>>4)*8+j].
// ---------------------------------------------------------------------------
__global__ void pack_w0_kernel(const float* __restrict__ W_ih, const float* __restrict__ W_hh,
                               const float* __restrict__ W_lin, const float* __restrict__ b_ih,
                               const float* __restrict__ b_hh,
                               uint4* __restrict__ w0, uint4* __restrict__ wl,
                               float4* __restrict__ bias0)
{
    int i = blockIdx.x * 256 + threadIdx.x;
    if (i < 36864) {                       // 576 w0 tiles x 64 lanes
        int lane = i & 63, tile = i >> 6;
        int w = tile / 36, rem = tile - w * 36;
        int g = rem / 12, kt = rem - g * 12;
        int n = g * 256 + (w << 4) + (lane & 15);
        int k0 = (kt << 5) + ((lane >> 4) << 3);
        const float* p = (k0 < 128) ? (W_ih + n * 128 + k0)
                                    : (W_hh + n * 256 + (k0 - 128));
        unsigned short h[8];
        #pragma unroll
        for (int j = 0; j < 8; ++j) h[j] = f2h(p[j]);
        uint4 v;
        v.x = (unsigned)h[0] | ((unsigned)h[1] << 16);
        v.y = (unsigned)h[2] | ((unsigned)h[3] << 16);
        v.z = (unsigned)h[4] | ((unsigned)h[5] << 16);
        v.w = (unsigned)h[6] | ((unsigned)h[7] << 16);
        w0[i] = v;
    } else if (i < 40960) {                // 64 wl tiles x 64 lanes
        int i2 = i - 36864;
        int lane = i2 & 63, tile = i2 >> 6;        // tile = nt*8 + kt
        int n = (tile >> 3) * 16 + (lane & 15);
        int k0 = ((tile & 7) << 5) + ((lane >> 4) << 3);
        const float* p = W_lin + n * 256 + k0;
        unsigned short h[8];
        #pragma unroll
        for (int j = 0; j < 8; ++j) h[j] = f2h(p[j]);
        uint4 v;
        v.x = (unsigned)h[0] | ((unsigned)h[1] << 16);
        v.y = (unsigned)h[2] | ((unsigned)h[3] << 16);
        v.z = (unsigned)h[4] | ((unsigned)h[5] << 16);
        v.w = (unsigned)h[6] | ((unsigned)h[7] << 16);
        wl[i2] = v;
    } else if (i < 41216) {
        int cb = i - 40960;
        bias0[cb] = make_float4(b_ih[cb] + b_hh[cb],
                                b_ih[256 + cb] + b_hh[256 + cb],
                                b_ih[512 + cb], b_hh[512 + cb]);
    }
}

// ---------------------------------------------------------------------------
// pack_wc: folded weights (fp32 fold, one fp16 round) + folded biases.
// tile idx = cg*32 + g*8 + kt; g: 0=r (W_ih_r@W_lin + W_hh_r), 1=z,
// 2=in (W_ihn@W_lin), 3=hn (W_hhn). (R5-verified)
// ---------------------------------------------------------------------------
__global__ void pack_wc_kernel(const float* __restrict__ W_ih, const float* __restrict__ W_hh,
                               const float* __restrict__ W_lin, const float* __restrict__ b_ih,
                               const float* __restrict__ b_hh, const float* __restrict__ b_lin,
                               uint4* __restrict__ wc, float4* __restrict__ bc)
{
    int i = blockIdx.x * 256 + threadIdx.x;
    if (i < 32768) {                       // 512 wc tiles x 64 lanes
        int lane = i & 63, tile = i >> 6;
        int w = tile >> 5, r = tile & 31;
        int g = r >> 3, kt = r & 7;
        int c = (w << 4) + (lane & 15);
        int k0 = (kt << 5) + ((lane >> 4) << 3);
        float s[8];
        if (g == 3) {
            #pragma unroll
            for (int j = 0; j < 8; ++j) s[j] = W_hh[(512 + c) * 256 + k0 + j];
        } else {
            int row = g * 256 + c;
            const float* wi = W_ih + row * 128;
            #pragma unroll
            for (int j = 0; j < 8; ++j) s[j] = 0.0f;
            for (int ii = 0; ii < 128; ++ii) {
                float wv = wi[ii];
                const float* wrow = W_lin + ii * 256 + k0;
                #pragma unroll
                for (int j = 0; j < 8; ++j) s[j] += wv * wrow[j];
            }
            if (g < 2) {
                #pragma unroll
                for (int j = 0; j < 8; ++j) s[j] += W_hh[row * 256 + k0 + j];
            }
        }
        unsigned short h[8];
        #pragma unroll
        for (int j = 0; j < 8; ++j) h[j] = f2h(s[j]);
        uint4 v;
        v.x = (unsigned)h[0] | ((unsigned)h[1] << 16);
        v.y = (unsigned)h[2] | ((unsigned)h[3] << 16);
        v.z = (unsigned)h[4] | ((unsigned)h[5] << 16);
        v.w = (unsigned)h[6] | ((unsigned)h[7] << 16);
        wc[i] = v;
    } else if (i < 33024) {
        int c = i - 32768;
        float d0 = 0.f, d1 = 0.f, d2 = 0.f;
        for (int ii = 0; ii < 128; ++ii) {
            float bl = b_lin[ii];
            d0 += bl * W_ih[c * 128 + ii];
            d1 += bl * W_ih[(256 + c) * 128 + ii];
            d2 += bl * W_ih[(512 + c) * 128 + ii];
        }
        bc[c] = make_float4(b_ih[c] + b_hh[c] + d0,
                            b_ih[256 + c] + b_hh[256 + c] + d1,
                            b_ih[512 + c] + d2,
                            b_hh[512 + c]);
    }
}

// ---------------------------------------------------------------------------
// Recurrence: 64 blocks x 512 thr (8 waves, 2/SIMD). Block owns 16 batch
// rows; wave w owns col-groups {w, w+8} (cols c0=w*16.., c1=128+w*16..).
// Residency per wave (64 gate tiles):
//   AGPR 32: r kt0-7, z kt0-7, both col-groups   (128 AGPRs, asm "+a" pinned)
//   LDS  16: in kt0-3, hn kt0-3, both col-groups (first-used kt<4)
//   streamed 16/step: in kt4-7, hn kt4-7 (first use kt=4 -> >=4-iter lead;
//       peak 16 live uint4 = 64 VGPRs)
// LDS (uint4): [0,1024) h-frag dbuf | [1024,1280) xbuf | [1280,9472)
// per-wave weight tiles (16/wave). One lgkm-only barrier per step.
// ---------------------------------------------------------------------------
__global__ __launch_bounds__(512, 2) void gru_kernel(
    const float* __restrict__ inputs,
    const float* __restrict__ hidden,
    const uint4* __restrict__ wc,
    const uint4* __restrict__ w0,
    const float4* __restrict__ bias0,
    const float4* __restrict__ bcp,
    float* __restrict__ out)
{
    __shared__ uint4 lds[9472];            // 151552 B

    const int tid  = threadIdx.x;
    const int lane = tid & 63;
    const int w    = tid >> 6;             // wave 0..7
    const int quad = lane >> 4;
    const int nc   = lane & 15;
    const int r0   = blockIdx.x << 4;
    const int c0   = (w << 4) + nc;
    const int c1   = 128 + c0;
    const float4 bc0 = bcp[c0];
    const float4 bc1 = bcp[c1];
    const uint4* wcw0 = wc + (size_t)w * 2048;        // 32 tiles * 64
    const uint4* wcw1 = wc + (size_t)(w + 8) * 2048;

    // ---- AGPR-pinned tiles: r kt0-7, z kt0-7 for both col-groups
    half8 wr0[8], wz0[8], wr1[8], wz1[8];
    #pragma unroll
    for (int kt = 0; kt < 8; ++kt) {
        wr0[kt] = ld_agpr(&wcw0[kt * 64 + lane]);
        wz0[kt] = ld_agpr(&wcw0[(8 + kt) * 64 + lane]);
        wr1[kt] = ld_agpr(&wcw1[kt * 64 + lane]);
        wz1[kt] = ld_agpr(&wcw1[(8 + kt) * 64 + lane]);
    }

    // ---- LDS-resident tiles: in kt0-3 (tiles 16-19), hn kt0-3 (tiles 24-27)
    // slot layout per cg: [0-3]=in kt0-3, [4-7]=hn kt0-3; cg1 at +512.
    const int wbase = 1280 + (w << 10);
    #pragma unroll
    for (int i = 0; i < 4; ++i) {
        lds[wbase + (i << 6) + lane]             = wcw0[(16 + i) * 64 + lane];
        lds[wbase + ((4 + i) << 6) + lane]       = wcw0[(24 + i) * 64 + lane];
        lds[wbase + 512 + (i << 6) + lane]       = wcw1[(16 + i) * 64 + lane];
        lds[wbase + 512 + ((4 + i) << 6) + lane] = wcw1[(24 + i) * 64 + lane];
    }

    // fp32 master hidden state: rows quad*4+d; [0..3]=c0, [4..7]=c1
    float hreg[8];
    #pragma unroll
    for (int d = 0; d < 4; ++d) {
        hreg[d]     = hidden[(r0 + (quad << 2) + d) * 256 + c0];
        hreg[4 + d] = hidden[(r0 + (quad << 2) + d) * 256 + c1];
    }

    // A-frag write addressing: A[m][k]: kt=k>>5, k'=k&31,
    // frag lane=(k'>>3)*16+m, j=k'&7; u16 idx=(kt*64+lane_f)*8+j
    unsigned short* lds_u16 = (unsigned short*)lds;
    const int kp  = ((w & 1) << 4) + nc;
    const int lf  = ((kp >> 3) << 4) + (quad << 2);
    const int hfb0 = (((w >> 1) * 64 + lf) << 3) + (kp & 7);
    const int hfb1 = (((4 + (w >> 1)) * 64 + lf) << 3) + (kp & 7);

    // init h(0) frags -> buf0
    for (int idx = tid; idx < 2048; idx += 512) {
        int ktl = idx >> 8;
        int rem = idx & 255;
        int lfr = rem >> 2, jg = rem & 3;
        int m = lfr & 15;
        int hc = ktl * 32 + (lfr >> 4) * 8 + jg * 2;
        const float* p = hidden + (r0 + m) * 256 + hc;
        unsigned pk = (unsigned)f2h(p[0]) | ((unsigned)f2h(p[1]) << 16);
        ((unsigned*)lds)[(ktl * 64 + lfr) * 4 + jg] = pk;
    }
    // init x frags -> xbuf
    for (int idx = tid; idx < 1024; idx += 512) {
        int kt = idx >> 8, lfr = (idx >> 2) & 63, jg = idx & 3;
        int m = lfr & 15;
        int k0 = (kt << 5) + ((lfr >> 4) << 3) + (jg << 1);
        const float* p = inputs + (r0 + m) * 128 + k0;
        unsigned pk = (unsigned)f2h(p[0]) | ((unsigned)f2h(p[1]) << 16);
        ((unsigned*)lds)[(1024 + (kt << 6) + lfr) * 4 + jg] = pk;
    }
    __syncthreads();

    unsigned short* Hout = (unsigned short*)out;

    // ---- t = 0: K=384 on [x|h] with original w0 (streamed once)
    {
        #pragma unroll
        for (int g2 = 0; g2 < 2; ++g2) {
            const uint4* ww = w0 + (size_t)(g2 ? (w + 8) : w) * 2304;  // 36*64
            floatx4 ar = {0.f,0.f,0.f,0.f}, az = {0.f,0.f,0.f,0.f};
            floatx4 ain = {0.f,0.f,0.f,0.f}, ahn = {0.f,0.f,0.f,0.f};
            #pragma unroll
            for (int kt = 0; kt < 12; ++kt) {
                half8 A = as_h8(kt < 4 ? lds[1024 + (kt << 6) + lane]
                                       : lds[((kt - 4) << 6) + lane]);
                ar = MFMA16(A, as_h8(ww[kt * 64 + lane]), ar);
                az = MFMA16(A, as_h8(ww[(12 + kt) * 64 + lane]), az);
                if (kt < 4)
                    ain = MFMA16(A, as_h8(ww[(24 + kt) * 64 + lane]), ain);
                else
                    ahn = MFMA16(A, as_h8(ww[(24 + kt) * 64 + lane]), ahn);
            }
            const int cc = g2 ? c1 : c0;
            const int hfb = g2 ? hfb1 : hfb0;
            float4 b0 = bias0[cc];
            #pragma unroll
            for (int d = 0; d < 4; ++d) {
                float rr = sigm(ar[d] + b0.x);
                float zz = sigm(az[d] + b0.y);
                float nn = tanh_fast(ain[d] + b0.z + rr * (ahn[d] + b0.w));
                float hnew = (1.0f - zz) * nn + zz * hreg[(g2 << 2) + d];
                hreg[(g2 << 2) + d] = hnew;
                unsigned short hu = f2h(hnew);
                lds_u16[4096 + hfb + (d << 3)] = hu;      // buf1
                Hout[((size_t)(r0 + (quad << 2) + d) << 8) + cc] = hu;
            }
        }
        bar_lgkm();
    }

    for (int t = 1; t < 256; ++t) {
        const int rb   = (t & 1) << 9;                 // read buf (uint4)
        const int wb16 = (((t + 1) & 1) << 9) << 3;    // write buf (u16)

        // opaque per-iteration pointers: streamed tiles cannot be hoisted
        const uint4* s0p = wcw0 + lane;
        const uint4* s1p = wcw1 + lane;
        asm("" : "+v"(s0p), "+v"(s1p));

        // streamed tiles: in kt4-7 (tiles 20-23), hn kt4-7 (tiles 28-31).
        // Batches at top and kt=1,2,3; first consumer kt=4 -> >=4-iter lead.
        uint4 si0[4], sh0[4], si1[4], sh1[4];
        si0[0] = s0p[20 * 64]; sh0[0] = s0p[28 * 64];
        si1[0] = s1p[20 * 64]; sh1[0] = s1p[28 * 64];

        floatx4 ar0 = {0.f,0.f,0.f,0.f}, az0 = {0.f,0.f,0.f,0.f};
        floatx4 ai0 = {0.f,0.f,0.f,0.f}, ah0 = {0.f,0.f,0.f,0.f};
        floatx4 ar1 = {0.f,0.f,0.f,0.f}, az1 = {0.f,0.f,0.f,0.f};
        floatx4 ai1 = {0.f,0.f,0.f,0.f}, ah1 = {0.f,0.f,0.f,0.f};

        #pragma unroll
        for (int kt = 0; kt < 8; ++kt) {
            half8 A = as_h8(lds[rb + (kt << 6) + lane]);
            if (kt == 1) {
                si0[1] = s0p[21 * 64]; sh0[1] = s0p[29 * 64];
                si1[1] = s1p[21 * 64]; sh1[1] = s1p[29 * 64];
            }
            if (kt == 2) {
                si0[2] = s0p[22 * 64]; sh0[2] = s0p[30 * 64];
                si1[2] = s1p[22 * 64]; sh1[2] = s1p[30 * 64];
            }
            if (kt == 3) {
                si0[3] = s0p[23 * 64]; sh0[3] = s0p[31 * 64];
                si1[3] = s1p[23 * 64]; sh1[3] = s1p[31 * 64];
            }
            ar0 = MFMA16(A, wr0[kt], ar0);
            ar1 = MFMA16(A, wr1[kt], ar1);
            az0 = MFMA16(A, wz0[kt], az0);
            az1 = MFMA16(A, wz1[kt], az1);
            half8 Bi0 = (kt < 4) ? as_h8(lds[wbase + (kt << 6) + lane])
                                 : as_h8(si0[kt - 4]);
            half8 Bi1 = (kt < 4) ? as_h8(lds[wbase + 512 + (kt << 6) + lane])
                                 : as_h8(si1[kt - 4]);
            ai0 = MFMA16(A, Bi0, ai0);
            ai1 = MFMA16(A, Bi1, ai1);
            half8 Bh0 = (kt < 4) ? as_h8(lds[wbase + ((4 + kt) << 6) + lane])
                                 : as_h8(sh0[kt - 4]);
            half8 Bh1 = (kt < 4) ? as_h8(lds[wbase + 512 + ((4 + kt) << 6) + lane])
                                 : as_h8(sh1[kt - 4]);
            ah0 = MFMA16(A, Bh0, ah0);
            ah1 = MFMA16(A, Bh1, ah1);
        }

        const size_t obase = (size_t)t * 1024 + r0 + (quad << 2);
        #pragma unroll
        for (int d = 0; d < 4; ++d) {
            float rr = sigm(ar0[d] + bc0.x);
            float zz = sigm(az0[d] + bc0.y);
            float nn = tanh_fast(ai0[d] + bc0.z + rr * (ah0[d] + bc0.w));
            float hnew = (1.0f - zz) * nn + zz * hreg[d];
            hreg[d] = hnew;
            unsigned short hu = f2h(hnew);
            lds_u16[wb16 + hfb0 + (d << 3)] = hu;
            Hout[((obase + d) << 8) + c0] = hu;
        }
        #pragma unroll
        for (int d = 0; d < 4; ++d) {
            float rr = sigm(ar1[d] + bc1.x);
            float zz = sigm(az1[d] + bc1.y);
            float nn = tanh_fast(ai1[d] + bc1.z + rr * (ah1[d] + bc1.w));
            float hnew = (1.0f - zz) * nn + zz * hreg[4 + d];
            hreg[4 + d] = hnew;
            unsigned short hu = f2h(hnew);
            lds_u16[wb16 + hfb1 + (d << 3)] = hu;
            Hout[((obase + d) << 8) + c1] = hu;
        }
        bar_lgkm();
    }
}

// ---------------------------------------------------------------------------
// y-GEMM: out[t,b,:] = H[t,b,:] @ W_lin^T + b_lin, fused BN partial sums.
// R10: 32 rows/block x 512 thr (8192 blocks). Waves 0-3 do rows 0-15,
// waves 4-7 rows 16-31; wave's col-pair = w&3. Cross-wave LDS combine ->
// one atomic pair per channel per block (halves atomic count vs R9).
// In-place over d_out (stages its 32 H-rows to LDS first).
// ---------------------------------------------------------------------------
__global__ __launch_bounds__(512, 2) void ygemm_kernel(
    const uint4* __restrict__ wl, const float* __restrict__ b_lin,
    float* __restrict__ out, float* __restrict__ stats)
{
    __shared__ unsigned short sh[32 * 264];          // 16896 B
    __shared__ float cst[4][2][16][2];               // 1024 B
    const int tid = threadIdx.x;
    const int t = blockIdx.x >> 5;
    const int r0 = (blockIdx.x & 31) << 5;           // 32 rows

    {
        int row = tid >> 4, seg = tid & 15;
        const uint4* src = (const uint4*)((const unsigned short*)out
                         + (((size_t)t << 10) + r0 + row) * 256) + (seg << 1);
        uint4 a = src[0], b = src[1];
        uint4* dst = (uint4*)(sh + row * 264 + (seg << 4));
        dst[0] = a; dst[1] = b;
    }
    __syncthreads();

    const int lane = tid & 63, w = tid >> 6;         // wave 0..7
    const int rowhalf = w >> 2;                      // 0: rows 0-15, 1: 16-31
    const int cgp = w & 3;                           // col-pair index
    const int quad = lane >> 4, nc = lane & 15;
    const int m = lane & 15, khi = lane >> 4;

    half8 B0[8], B1[8];
    #pragma unroll
    for (int kt = 0; kt < 8; ++kt) {
        B0[kt] = as_h8(wl[(((cgp << 1) + 0) * 8 + kt) * 64 + lane]);
        B1[kt] = as_h8(wl[(((cgp << 1) + 1) * 8 + kt) * 64 + lane]);
    }
    floatx4 a0 = {0.f,0.f,0.f,0.f}, a1 = {0.f,0.f,0.f,0.f};
    #pragma unroll
    for (int kt = 0; kt < 8; ++kt) {
        half8 A = *(const half8*)(sh + ((rowhalf << 4) + m) * 264 + (kt << 5) + (khi << 3));
        a0 = MFMA16(A, B0[kt], a0);
        a1 = MFMA16(A, B1[kt], a1);
    }
    float s1g[2], s2g[2];
    #pragma unroll
    for (int g = 0; g < 2; ++g) {
        floatx4 acc = g ? a1 : a0;
        int i = (((cgp << 1) + g) << 4) + nc;
        float bl = b_lin[i];
        float s1 = 0.f, s2 = 0.f;
        float* orow = out + (((size_t)t << 10) + r0 + (rowhalf << 4) + (quad << 2)) * 128 + i;
        #pragma unroll
        for (int d = 0; d < 4; ++d) {
            float y = acc[d] + bl;
            orow[(size_t)d << 7] = y;
            s1 += y; s2 += y * y;
        }
        s1 += __shfl_xor(s1, 16); s1 += __shfl_xor(s1, 32);
        s2 += __shfl_xor(s2, 16); s2 += __shfl_xor(s2, 32);
        s1g[g] = s1; s2g[g] = s2;
    }
    // waves 4-7 hand their 16-row sums to waves 0-3; one atomic pair/channel
    if (rowhalf == 1 && lane < 16) {
        cst[cgp][0][lane][0] = s1g[0]; cst[cgp][0][lane][1] = s2g[0];
        cst[cgp][1][lane][0] = s1g[1]; cst[cgp][1][lane][1] = s2g[1];
    }
    __syncthreads();
    if (rowhalf == 0 && lane < 16) {
        #pragma unroll
        for (int g = 0; g < 2; ++g) {
            int si = ((t << 7) + (((cgp << 1) + g) << 4) + lane) << 1;
            atomicAdd(&stats[si],     s1g[g] + cst[cgp][g][lane][0]);
            atomicAdd(&stats[si + 1], s2g[g] + cst[cgp][g][lane][1]);
        }
    }
}

// ---------------------------------------------------------------------------
// Normalize: in-place BN from raw sums. Biased variance, eps inside sqrt.
// ---------------------------------------------------------------------------
__global__ void norm_kernel(float* __restrict__ out, const float* __restrict__ stats)
{
    __shared__ float smean[128], sscale[128];
    int t = blockIdx.x >> 2, q = blockIdx.x & 3;
    int tid = threadIdx.x;
    if (tid < 128) {
        int si = ((t << 7) + tid) << 1;
        float mean = stats[si] * (1.0f / 1024.0f);
        float var = stats[si + 1] * (1.0f / 1024.0f) - mean * mean;
        smean[tid] = mean;
        sscale[tid] = rsqrtf(var + EPS_BN);
    }
    __syncthreads();
    float4* p = (float4*)(out + ((size_t)t << 17) + ((size_t)q << 15));
    for (int i = tid; i < 8192; i += 256) {
        int cc = (i & 31) << 2;
        float4 v = p[i];
        v.x = (v.x - smean[cc])     * sscale[cc];
        v.y = (v.y - smean[cc + 1]) * sscale[cc + 1];
        v.z = (v.z - smean[cc + 2]) * sscale[cc + 2];
        v.w = (v.w - smean[cc + 3]) * sscale[cc + 3];
        p[i] = v;
    }
}

extern "C" void kernel_launch(void* const* d_in, const int* in_sizes, int n_in,
                              void* d_out, int out_size, void* d_ws, size_t ws_size,
                              hipStream_t stream) {
    (void)in_sizes; (void)n_in; (void)out_size; (void)ws_size;
    const float* inputs = (const float*)d_in[0];
    const float* hidden = (const float*)d_in[1];
    const float* W_ih   = (const float*)d_in[2];
    const float* b_ih   = (const float*)d_in[3];
    const float* W_hh   = (const float*)d_in[4];
    const float* b_hh   = (const float*)d_in[5];
    const float* W_lin  = (const float*)d_in[6];
    const float* b_lin  = (const float*)d_in[7];

    char* ws = (char*)d_ws;
    uint4*  wcp   = (uint4*)(ws + WS_WC);
    uint4*  w0p   = (uint4*)(ws + WS_W0);
    uint4*  wlp   = (uint4*)(ws + WS_WL);
    float4* bias0 = (float4*)(ws + WS_B0);
    float4* bcp   = (float4*)(ws + WS_BC);
    float*  stats = (float*)(ws + WS_ST);

    hipMemsetAsync(stats, 0, 262144, stream);
    pack_w0_kernel<<<161, 256, 0, stream>>>(W_ih, W_hh, W_lin, b_ih, b_hh, w0p, wlp, bias0);
    pack_wc_kernel<<<129, 256, 0, stream>>>(W_ih, W_hh, W_lin, b_ih, b_hh, b_lin, wcp, bcp);
    gru_kernel<<<64, 512, 0, stream>>>(inputs, hidden, wcp, w0p, bias0, bcp, (float*)d_out);
    ygemm_kernel<<<8192, 512, 0, stream>>>(wlp, b_lin, (float*)d_out, stats);
    norm_kernel<<<1024, 256, 0, stream>>>((float*)d_out, stats);
}

// Round 5
// 1000.864 us; speedup vs baseline: 1.5064x; 1.0344x over previous
//
#include <hip/hip_runtime.h>

// ---------------------------------------------------------------------------
// GRU (T=256, B=1024, IN=128, H=256) + per-step BatchNorm, MI355X.
// R10->R11: epilogue collapsed. ygemm+stats+norm+memset replaced by ONE
// yfused kernel: grid=256 (one block per timestep, 1/CU), 512 thr. Block
// GEMMs its whole 1024x256 H[t] against W_lin (64KB LDS), holds y[t]
// (1024x128 = 128 packed-fp16 regs/thread) in AGPRs via the "+a" pin (the
// unified file is idle here), reduces s1/s2 across waves in LDS, then
// normalizes in-register and writes fp32 out once. Eliminates the norm
// kernel's 268MB round trip, all stats atomics, the memset, 2 launches.
// pack_w0+pack_wc merged into one launch. gru untouched (819us, proven;
// 128 VGPR + 128 AGPR = exactly the 256/wave cap at 8 waves/CU).
// ---------------------------------------------------------------------------

typedef _Float16 half8 __attribute__((ext_vector_type(8)));
typedef float floatx4 __attribute__((ext_vector_type(4)));
typedef unsigned uintx4 __attribute__((ext_vector_type(4)));

#define EPS_BN 1e-5f

// ws layout (bytes):
//   [0,       524288)   wc: folded gate weights, 16 cgs x 32 tiles x 1 KB
//   [524288, 1114112)   w0: step-0 weights, 16 cgs x 36 tiles x 1 KB
//   [1114112,1179648)   wl: W_lin B-frags, 64 tiles x 1 KB
//   [1179648,1183744)   bias0: 256 x float4
//   [1183744,1187840)   bc: 256 x float4 folded biases
#define WS_WC 0
#define WS_W0 524288
#define WS_WL 1114112
#define WS_B0 1179648
#define WS_BC 1183744

static __device__ __forceinline__ unsigned short f2h(float f) {
    union { _Float16 h; unsigned short u; } v;
    v.h = (_Float16)f;                      // v_cvt_f16_f32, RNE
    return v.u;
}
static __device__ __forceinline__ unsigned pack2h(float a, float b) {
    return (unsigned)f2h(a) | ((unsigned)f2h(b) << 16);
}
static __device__ __forceinline__ float2 up2(unsigned u) {
    union { unsigned v; _Float16 h[2]; } x; x.v = u;
    return make_float2((float)x.h[0], (float)x.h[1]);
}
static __device__ __forceinline__ half8 as_h8(uint4 v) {
    union { uint4 u; half8 h; } x; x.u = v; return x.h;
}
// Load a 16B weight fragment and force it into AGPRs (opaque, non-remat).
static __device__ __forceinline__ half8 ld_agpr(const uint4* p) {
    uintx4 v = *(const uintx4*)p;
    asm volatile("; wpin" : "+a"(v));
    union { uintx4 u; half8 h; } x; x.u = v; return x.h;
}
// Fast activations: v_rcp_f32 + v_exp_f32 (1 ulp each).
static __device__ __forceinline__ float sigm(float x) {
    return __builtin_amdgcn_rcpf(1.0f + __builtin_amdgcn_exp2f(-1.442695041f * x));
}
static __device__ __forceinline__ float tanh_fast(float x) {
    return 1.0f - 2.0f * __builtin_amdgcn_rcpf(1.0f + __builtin_amdgcn_exp2f(2.885390082f * x));
}
// Workgroup barrier that drains LDS only (no vmcnt(0) store-drain).
static __device__ __forceinline__ void bar_lgkm() {
    asm volatile("s_waitcnt lgkmcnt(0)\n\ts_barrier" ::: "memory");
}
#define MFMA16(A, B, C) __builtin_amdgcn_mfma_f32_16x16x32_f16((A), (B), (C), 0, 0, 0)

// ---------------------------------------------------------------------------
// pack_all: [blocks 0..160] original weights -> w0 tiles + wl + bias0;
// [blocks 161..289] folded weights -> wc tiles + folded biases bc.
// B-frag 16x16x32: lane l holds B[n0+(l&15)][k0+(l>>4)*8+j]. (R3/R5-verified)
// ---------------------------------------------------------------------------
__global__ void pack_all_kernel(const float* __restrict__ W_ih, const float* __restrict__ W_hh,
                                const float* __restrict__ W_lin, const float* __restrict__ b_ih,
                                const float* __restrict__ b_hh, const float* __restrict__ b_lin,
                                uint4* __restrict__ w0, uint4* __restrict__ wl,
                                float4* __restrict__ bias0,
                                uint4* __restrict__ wc, float4* __restrict__ bc)
{
    if (blockIdx.x < 161) {
        int i = blockIdx.x * 256 + threadIdx.x;
        if (i < 36864) {                       // 576 w0 tiles x 64 lanes
            int lane = i & 63, tile = i >> 6;
            int w = tile / 36, rem = tile - w * 36;
            int g = rem / 12, kt = rem - g * 12;
            int n = g * 256 + (w << 4) + (lane & 15);
            int k0 = (kt << 5) + ((lane >> 4) << 3);
            const float* p = (k0 < 128) ? (W_ih + n * 128 + k0)
                                        : (W_hh + n * 256 + (k0 - 128));
            unsigned short h[8];
            #pragma unroll
            for (int j = 0; j < 8; ++j) h[j] = f2h(p[j]);
            uint4 v;
            v.x = (unsigned)h[0] | ((unsigned)h[1] << 16);
            v.y = (unsigned)h[2] | ((unsigned)h[3] << 16);
            v.z = (unsigned)h[4] | ((unsigned)h[5] << 16);
            v.w = (unsigned)h[6] | ((unsigned)h[7] << 16);
            w0[i] = v;
        } else if (i < 40960) {                // 64 wl tiles x 64 lanes
            int i2 = i - 36864;
            int lane = i2 & 63, tile = i2 >> 6;        // tile = nt*8 + kt
            int n = (tile >> 3) * 16 + (lane & 15);
            int k0 = ((tile & 7) << 5) + ((lane >> 4) << 3);
            const float* p = W_lin + n * 256 + k0;
            unsigned short h[8];
            #pragma unroll
            for (int j = 0; j < 8; ++j) h[j] = f2h(p[j]);
            uint4 v;
            v.x = (unsigned)h[0] | ((unsigned)h[1] << 16);
            v.y = (unsigned)h[2] | ((unsigned)h[3] << 16);
            v.z = (unsigned)h[4] | ((unsigned)h[5] << 16);
            v.w = (unsigned)h[6] | ((unsigned)h[7] << 16);
            wl[i2] = v;
        } else if (i < 41216) {
            int cb = i - 40960;
            bias0[cb] = make_float4(b_ih[cb] + b_hh[cb],
                                    b_ih[256 + cb] + b_hh[256 + cb],
                                    b_ih[512 + cb], b_hh[512 + cb]);
        }
        return;
    }
    int i = (blockIdx.x - 161) * 256 + threadIdx.x;
    if (i < 32768) {                       // 512 wc tiles x 64 lanes
        int lane = i & 63, tile = i >> 6;
        int w = tile >> 5, r = tile & 31;
        int g = r >> 3, kt = r & 7;
        int c = (w << 4) + (lane & 15);
        int k0 = (kt << 5) + ((lane >> 4) << 3);
        float s[8];
        if (g == 3) {
            #pragma unroll
            for (int j = 0; j < 8; ++j) s[j] = W_hh[(512 + c) * 256 + k0 + j];
        } else {
            int row = g * 256 + c;
            const float* wi = W_ih + row * 128;
            #pragma unroll
            for (int j = 0; j < 8; ++j) s[j] = 0.0f;
            for (int ii = 0; ii < 128; ++ii) {
                float wv = wi[ii];
                const float* wrow = W_lin + ii * 256 + k0;
                #pragma unroll
                for (int j = 0; j < 8; ++j) s[j] += wv * wrow[j];
            }
            if (g < 2) {
                #pragma unroll
                for (int j = 0; j < 8; ++j) s[j] += W_hh[row * 256 + k0 + j];
            }
        }
        unsigned short h[8];
        #pragma unroll
        for (int j = 0; j < 8; ++j) h[j] = f2h(s[j]);
        uint4 v;
        v.x = (unsigned)h[0] | ((unsigned)h[1] << 16);
        v.y = (unsigned)h[2] | ((unsigned)h[3] << 16);
        v.z = (unsigned)h[4] | ((unsigned)h[5] << 16);
        v.w = (unsigned)h[6] | ((unsigned)h[7] << 16);
        wc[i] = v;
    } else if (i < 33024) {
        int c = i - 32768;
        float d0 = 0.f, d1 = 0.f, d2 = 0.f;
        for (int ii = 0; ii < 128; ++ii) {
            float bl = b_lin[ii];
            d0 += bl * W_ih[c * 128 + ii];
            d1 += bl * W_ih[(256 + c) * 128 + ii];
            d2 += bl * W_ih[(512 + c) * 128 + ii];
        }
        bc[c] = make_float4(b_ih[c] + b_hh[c] + d0,
                            b_ih[256 + c] + b_hh[256 + c] + d1,
                            b_ih[512 + c] + d2,
                            b_hh[512 + c]);
    }
}

// ---------------------------------------------------------------------------
// Recurrence: 64 blocks x 512 thr (8 waves, 2/SIMD). Block owns 16 batch
// rows; wave w owns col-groups {w, w+8} (cols c0=w*16.., c1=128+w*16..).
// Residency per wave (64 gate tiles):
//   AGPR 32: r kt0-7, z kt0-7, both col-groups   (128 AGPRs, asm "+a" pinned)
//   LDS  16: in kt0-3, hn kt0-3, both col-groups (first-used kt<4)
//   streamed 16/step: in kt4-7, hn kt4-7 (first use kt=4 -> >=4-iter lead;
//       peak 16 live uint4 = 64 VGPRs)
// LDS (uint4): [0,1024) h-frag dbuf | [1024,1280) xbuf | [1280,9472)
// per-wave weight tiles (16/wave). One lgkm-only barrier per step.
// (R9-verified, untouched)
// ---------------------------------------------------------------------------
__global__ __launch_bounds__(512, 2) void gru_kernel(
    const float* __restrict__ inputs,
    const float* __restrict__ hidden,
    const uint4* __restrict__ wc,
    const uint4* __restrict__ w0,
    const float4* __restrict__ bias0,
    const float4* __restrict__ bcp,
    float* __restrict__ out)
{
    __shared__ uint4 lds[9472];            // 151552 B

    const int tid  = threadIdx.x;
    const int lane = tid & 63;
    const int w    = tid >> 6;             // wave 0..7
    const int quad = lane >> 4;
    const int nc   = lane & 15;
    const int r0   = blockIdx.x << 4;
    const int c0   = (w << 4) + nc;
    const int c1   = 128 + c0;
    const float4 bc0 = bcp[c0];
    const float4 bc1 = bcp[c1];
    const uint4* wcw0 = wc + (size_t)w * 2048;        // 32 tiles * 64
    const uint4* wcw1 = wc + (size_t)(w + 8) * 2048;

    // ---- AGPR-pinned tiles: r kt0-7, z kt0-7 for both col-groups
    half8 wr0[8], wz0[8], wr1[8], wz1[8];
    #pragma unroll
    for (int kt = 0; kt < 8; ++kt) {
        wr0[kt] = ld_agpr(&wcw0[kt * 64 + lane]);
        wz0[kt] = ld_agpr(&wcw0[(8 + kt) * 64 + lane]);
        wr1[kt] = ld_agpr(&wcw1[kt * 64 + lane]);
        wz1[kt] = ld_agpr(&wcw1[(8 + kt) * 64 + lane]);
    }

    // ---- LDS-resident tiles: in kt0-3 (tiles 16-19), hn kt0-3 (tiles 24-27)
    // slot layout per cg: [0-3]=in kt0-3, [4-7]=hn kt0-3; cg1 at +512.
    const int wbase = 1280 + (w << 10);
    #pragma unroll
    for (int i = 0; i < 4; ++i) {
        lds[wbase + (i << 6) + lane]             = wcw0[(16 + i) * 64 + lane];
        lds[wbase + ((4 + i) << 6) + lane]       = wcw0[(24 + i) * 64 + lane];
        lds[wbase + 512 + (i << 6) + lane]       = wcw1[(16 + i) * 64 + lane];
        lds[wbase + 512 + ((4 + i) << 6) + lane] = wcw1[(24 + i) * 64 + lane];
    }

    // fp32 master hidden state: rows quad*4+d; [0..3]=c0, [4..7]=c1
    float hreg[8];
    #pragma unroll
    for (int d = 0; d < 4; ++d) {
        hreg[d]     = hidden[(r0 + (quad << 2) + d) * 256 + c0];
        hreg[4 + d] = hidden[(r0 + (quad << 2) + d) * 256 + c1];
    }

    // A-frag write addressing: A[m][k]: kt=k>>5, k'=k&31,
    // frag lane=(k'>>3)*16+m, j=k'&7; u16 idx=(kt*64+lane_f)*8+j
    unsigned short* lds_u16 = (unsigned short*)lds;
    const int kp  = ((w & 1) << 4) + nc;
    const int lf  = ((kp >> 3) << 4) + (quad << 2);
    const int hfb0 = (((w >> 1) * 64 + lf) << 3) + (kp & 7);
    const int hfb1 = (((4 + (w >> 1)) * 64 + lf) << 3) + (kp & 7);

    // init h(0) frags -> buf0
    for (int idx = tid; idx < 2048; idx += 512) {
        int ktl = idx >> 8;
        int rem = idx & 255;
        int lfr = rem >> 2, jg = rem & 3;
        int m = lfr & 15;
        int hc = ktl * 32 + (lfr >> 4) * 8 + jg * 2;
        const float* p = hidden + (r0 + m) * 256 + hc;
        unsigned pk = (unsigned)f2h(p[0]) | ((unsigned)f2h(p[1]) << 16);
        ((unsigned*)lds)[(ktl * 64 + lfr) * 4 + jg] = pk;
    }
    // init x frags -> xbuf
    for (int idx = tid; idx < 1024; idx += 512) {
        int kt = idx >> 8, lfr = (idx >> 2) & 63, jg = idx & 3;
        int m = lfr & 15;
        int k0 = (kt << 5) + ((lfr >> 4) << 3) + (jg << 1);
        const float* p = inputs + (r0 + m) * 128 + k0;
        unsigned pk = (unsigned)f2h(p[0]) | ((unsigned)f2h(p[1]) << 16);
        ((unsigned*)lds)[(1024 + (kt << 6) + lfr) * 4 + jg] = pk;
    }
    __syncthreads();

    unsigned short* Hout = (unsigned short*)out;

    // ---- t = 0: K=384 on [x|h] with original w0 (streamed once)
    {
        #pragma unroll
        for (int g2 = 0; g2 < 2; ++g2) {
            const uint4* ww = w0 + (size_t)(g2 ? (w + 8) : w) * 2304;  // 36*64
            floatx4 ar = {0.f,0.f,0.f,0.f}, az = {0.f,0.f,0.f,0.f};
            floatx4 ain = {0.f,0.f,0.f,0.f}, ahn = {0.f,0.f,0.f,0.f};
            #pragma unroll
            for (int kt = 0; kt < 12; ++kt) {
                half8 A = as_h8(kt < 4 ? lds[1024 + (kt << 6) + lane]
                                       : lds[((kt - 4) << 6) + lane]);
                ar = MFMA16(A, as_h8(ww[kt * 64 + lane]), ar);
                az = MFMA16(A, as_h8(ww[(12 + kt) * 64 + lane]), az);
                if (kt < 4)
                    ain = MFMA16(A, as_h8(ww[(24 + kt) * 64 + lane]), ain);
                else
                    ahn = MFMA16(A, as_h8(ww[(24 + kt) * 64 + lane]), ahn);
            }
            const int cc = g2 ? c1 : c0;
            const int hfb = g2 ? hfb1 : hfb0;
            float4 b0 = bias0[cc];
            #pragma unroll
            for (int d = 0; d < 4; ++d) {
                float rr = sigm(ar[d] + b0.x);
                float zz = sigm(az[d] + b0.y);
                float nn = tanh_fast(ain[d] + b0.z + rr * (ahn[d] + b0.w));
                float hnew = (1.0f - zz) * nn + zz * hreg[(g2 << 2) + d];
                hreg[(g2 << 2) + d] = hnew;
                unsigned short hu = f2h(hnew);
                lds_u16[4096 + hfb + (d << 3)] = hu;      // buf1
                Hout[((size_t)(r0 + (quad << 2) + d) << 8) + cc] = hu;
            }
        }
        bar_lgkm();
    }

    for (int t = 1; t < 256; ++t) {
        const int rb   = (t & 1) << 9;                 // read buf (uint4)
        const int wb16 = (((t + 1) & 1) << 9) << 3;    // write buf (u16)

        // opaque per-iteration pointers: streamed tiles cannot be hoisted
        const uint4* s0p = wcw0 + lane;
        const uint4* s1p = wcw1 + lane;
        asm("" : "+v"(s0p), "+v"(s1p));

        // streamed tiles: in kt4-7 (tiles 20-23), hn kt4-7 (tiles 28-31).
        // Batches at top and kt=1,2,3; first consumer kt=4 -> >=4-iter lead.
        uint4 si0[4], sh0[4], si1[4], sh1[4];
        si0[0] = s0p[20 * 64]; sh0[0] = s0p[28 * 64];
        si1[0] = s1p[20 * 64]; sh1[0] = s1p[28 * 64];

        floatx4 ar0 = {0.f,0.f,0.f,0.f}, az0 = {0.f,0.f,0.f,0.f};
        floatx4 ai0 = {0.f,0.f,0.f,0.f}, ah0 = {0.f,0.f,0.f,0.f};
        floatx4 ar1 = {0.f,0.f,0.f,0.f}, az1 = {0.f,0.f,0.f,0.f};
        floatx4 ai1 = {0.f,0.f,0.f,0.f}, ah1 = {0.f,0.f,0.f,0.f};

        #pragma unroll
        for (int kt = 0; kt < 8; ++kt) {
            half8 A = as_h8(lds[rb + (kt << 6) + lane]);
            if (kt == 1) {
                si0[1] = s0p[21 * 64]; sh0[1] = s0p[29 * 64];
                si1[1] = s1p[21 * 64]; sh1[1] = s1p[29 * 64];
            }
            if (kt == 2) {
                si0[2] = s0p[22 * 64]; sh0[2] = s0p[30 * 64];
                si1[2] = s1p[22 * 64]; sh1[2] = s1p[30 * 64];
            }
            if (kt == 3) {
                si0[3] = s0p[23 * 64]; sh0[3] = s0p[31 * 64];
                si1[3] = s1p[23 * 64]; sh1[3] = s1p[31 * 64];
            }
            ar0 = MFMA16(A, wr0[kt], ar0);
            ar1 = MFMA16(A, wr1[kt], ar1);
            az0 = MFMA16(A, wz0[kt], az0);
            az1 = MFMA16(A, wz1[kt], az1);
            half8 Bi0 = (kt < 4) ? as_h8(lds[wbase + (kt << 6) + lane])
                                 : as_h8(si0[kt - 4]);
            half8 Bi1 = (kt < 4) ? as_h8(lds[wbase + 512 + (kt << 6) + lane])
                                 : as_h8(si1[kt - 4]);
            ai0 = MFMA16(A, Bi0, ai0);
            ai1 = MFMA16(A, Bi1, ai1);
            half8 Bh0 = (kt < 4) ? as_h8(lds[wbase + ((4 + kt) << 6) + lane])
                                 : as_h8(sh0[kt - 4]);
            half8 Bh1 = (kt < 4) ? as_h8(lds[wbase + 512 + ((4 + kt) << 6) + lane])
                                 : as_h8(sh1[kt - 4]);
            ah0 = MFMA16(A, Bh0, ah0);
            ah1 = MFMA16(A, Bh1, ah1);
        }

        const size_t obase = (size_t)t * 1024 + r0 + (quad << 2);
        #pragma unroll
        for (int d = 0; d < 4; ++d) {
            float rr = sigm(ar0[d] + bc0.x);
            float zz = sigm(az0[d] + bc0.y);
            float nn = tanh_fast(ai0[d] + bc0.z + rr * (ah0[d] + bc0.w));
            float hnew = (1.0f - zz) * nn + zz * hreg[d];
            hreg[d] = hnew;
            unsigned short hu = f2h(hnew);
            lds_u16[wb16 + hfb0 + (d << 3)] = hu;
            Hout[((obase + d) << 8) + c0] = hu;
        }
        #pragma unroll
        for (int d = 0; d < 4; ++d) {
            float rr = sigm(ar1[d] + bc1.x);
            float zz = sigm(az1[d] + bc1.y);
            float nn = tanh_fast(ai1[d] + bc1.z + rr * (ah1[d] + bc1.w));
            float hnew = (1.0f - zz) * nn + zz * hreg[4 + d];
            hreg[4 + d] = hnew;
            unsigned short hu = f2h(hnew);
            lds_u16[wb16 + hfb1 + (d << 3)] = hu;
            Hout[((obase + d) << 8) + c1] = hu;
        }
        bar_lgkm();
    }
}

// ---------------------------------------------------------------------------
// yfused: one block per timestep t (grid 256, 1/CU, 512 thr = 8 waves).
// Phase 1: wave w computes y rows [w*128, w*128+128) x all 128 cols:
//   A-frags straight from H global (u16), B from 64KB LDS (all W_lin tiles),
//   y packed fp16 -> 32 uintx4/thread pinned in AGPRs; s1/s2 fp32 per lane.
// Phase 2: shfl + LDS reduce -> mean/scale per channel.
// Phase 3: unpack AGPR y, normalize, write fp32 out. In-place over d_out:
//   all H reads are consumed by phase-1 MFMAs before the stats barrier.
// ---------------------------------------------------------------------------
__global__ __launch_bounds__(512, 2) void yfused_kernel(
    const uint4* __restrict__ wl, const float* __restrict__ b_lin,
    float* __restrict__ out)
{
    __shared__ uint4 bfr[4096];            // 64 KB: 64 W_lin tiles
    __shared__ float sred[8][256];         // 8 KB: per-wave s1[128] | s2[128]
    __shared__ float snorm[256];           // mean[128] | scale[128]

    const int tid  = threadIdx.x;
    const int lane = tid & 63;
    const int w    = tid >> 6;
    const int quad = lane >> 4;
    const int nc   = lane & 15;
    const int t    = blockIdx.x;

    const unsigned short* H = (const unsigned short*)out + (size_t)t * 262144;
    float* Y = out + (size_t)t * 131072;

    // stage all W_lin B-frags
    #pragma unroll
    for (int i = 0; i < 8; ++i)
        bfr[(i << 9) + tid] = wl[(i << 9) + tid];

    float blv[8];
    #pragma unroll
    for (int c = 0; c < 8; ++c) blv[c] = b_lin[(c << 4) + nc];

    __syncthreads();

    const int rw0 = w << 7;                // wave's first row of 128
    float s1[8], s2[8];
    #pragma unroll
    for (int c = 0; c < 8; ++c) { s1[c] = 0.f; s2[c] = 0.f; }
    uintx4 ypk[32];

    #pragma unroll
    for (int s = 0; s < 8; ++s) {
        const unsigned short* hrow = H + (size_t)(rw0 + (s << 4) + nc) * 256 + (quad << 3);
        uint4 A[8];
        #pragma unroll
        for (int kt = 0; kt < 8; ++kt)
            A[kt] = *(const uint4*)(hrow + (kt << 5));
        unsigned te0 = 0, te1 = 0;
        #pragma unroll
        for (int c = 0; c < 8; ++c) {
            floatx4 acc = {0.f, 0.f, 0.f, 0.f};
            #pragma unroll
            for (int kt = 0; kt < 8; ++kt)
                acc = MFMA16(as_h8(A[kt]), as_h8(bfr[(((c << 3) + kt) << 6) + lane]), acc);
            float y0 = acc[0] + blv[c], y1 = acc[1] + blv[c];
            float y2 = acc[2] + blv[c], y3 = acc[3] + blv[c];
            s1[c] += (y0 + y1) + (y2 + y3);
            s2[c] += (y0 * y0 + y1 * y1) + (y2 * y2 + y3 * y3);
            unsigned q0 = pack2h(y0, y1), q1 = pack2h(y2, y3);
            if ((c & 1) == 0) { te0 = q0; te1 = q1; }
            else {
                uintx4 v; v[0] = te0; v[1] = te1; v[2] = q0; v[3] = q1;
                asm volatile("; ypin" : "+a"(v));
                ypk[(s << 2) + (c >> 1)] = v;
            }
        }
    }

    // cross-quad then cross-wave stats reduce
    #pragma unroll
    for (int c = 0; c < 8; ++c) {
        s1[c] += __shfl_xor(s1[c], 16); s1[c] += __shfl_xor(s1[c], 32);
        s2[c] += __shfl_xor(s2[c], 16); s2[c] += __shfl_xor(s2[c], 32);
    }
    if (lane < 16) {
        #pragma unroll
        for (int c = 0; c < 8; ++c) {
            sred[w][(c << 4) + lane]       = s1[c];
            sred[w][128 + (c << 4) + lane] = s2[c];
        }
    }
    __syncthreads();
    if (tid < 128) {
        float a1 = 0.f, a2 = 0.f;
        #pragma unroll
        for (int w2 = 0; w2 < 8; ++w2) {
            a1 += sred[w2][tid];
            a2 += sred[w2][128 + tid];
        }
        float mean = a1 * (1.0f / 1024.0f);
        float var  = a2 * (1.0f / 1024.0f) - mean * mean;
        snorm[tid]       = mean;
        snorm[128 + tid] = rsqrtf(var + EPS_BN);
    }
    __syncthreads();

    float mn[8], scl[8];
    #pragma unroll
    for (int c = 0; c < 8; ++c) {
        mn[c]  = snorm[(c << 4) + nc];
        scl[c] = snorm[128 + (c << 4) + nc];
    }

    #pragma unroll
    for (int s = 0; s < 8; ++s) {
        float* yrow = Y + (size_t)(rw0 + (s << 4) + (quad << 2)) * 128 + nc;
        #pragma unroll
        for (int cp = 0; cp < 4; ++cp) {
            uintx4 v = ypk[(s << 2) + cp];
            const int c0 = cp << 1, c1 = c0 + 1;
            float2 a01 = up2(v[0]), a23 = up2(v[1]);   // col-tile c0, d0..3
            float2 b01 = up2(v[2]), b23 = up2(v[3]);   // col-tile c1, d0..3
            const int o0 = cp << 5, o1 = o0 + 16;
            yrow[0 * 128 + o0] = (a01.x - mn[c0]) * scl[c0];
            yrow[1 * 128 + o0] = (a01.y - mn[c0]) * scl[c0];
            yrow[2 * 128 + o0] = (a23.x - mn[c0]) * scl[c0];
            yrow[3 * 128 + o0] = (a23.y - mn[c0]) * scl[c0];
            yrow[0 * 128 + o1] = (b01.x - mn[c1]) * scl[c1];
            yrow[1 * 128 + o1] = (b01.y - mn[c1]) * scl[c1];
            yrow[2 * 128 + o1] = (b23.x - mn[c1]) * scl[c1];
            yrow[3 * 128 + o1] = (b23.y - mn[c1]) * scl[c1];
        }
    }
}

extern "C" void kernel_launch(void* const* d_in, const int* in_sizes, int n_in,
                              void* d_out, int out_size, void* d_ws, size_t ws_size,
                              hipStream_t stream) {
    (void)in_sizes; (void)n_in; (void)out_size; (void)ws_size;
    const float* inputs = (const float*)d_in[0];
    const float* hidden = (const float*)d_in[1];
    const float* W_ih   = (const float*)d_in[2];
    const float* b_ih   = (const float*)d_in[3];
    const float* W_hh   = (const float*)d_in[4];
    const float* b_hh   = (const float*)d_in[5];
    const float* W_lin  = (const float*)d_in[6];
    const float* b_lin  = (const float*)d_in[7];

    char* ws = (char*)d_ws;
    uint4*  wcp   = (uint4*)(ws + WS_WC);
    uint4*  w0p   = (uint4*)(ws + WS_W0);
    uint4*  wlp   = (uint4*)(ws + WS_WL);
    float4* bias0 = (float4*)(ws + WS_B0);
    float4* bcp   = (float4*)(ws + WS_BC);

    pack_all_kernel<<<290, 256, 0, stream>>>(W_ih, W_hh, W_lin, b_ih, b_hh, b_lin,
                                             w0p, wlp, bias0, wcp, bcp);
    gru_kernel<<<64, 512, 0, stream>>>(inputs, hidden, wcp, w0p, bias0, bcp, (float*)d_out);
    yfused_kernel<<<256, 512, 0, stream>>>(wlp, b_lin, (float*)d_out);
}